// Round 2
// baseline (202527.551 us; speedup 1.0000x reference)
//
#include <hip/hip_runtime.h>

typedef unsigned short u16;
typedef short s16x8 __attribute__((ext_vector_type(8)));
typedef float f32x4 __attribute__((ext_vector_type(4)));

#define DEV static __device__ __forceinline__

DEV float bf2f(u16 h){ union{unsigned u;float f;} v; v.u=((unsigned)h)<<16; return v.f; }
DEV u16 f2bf(float f){ union{float f;unsigned u;} v; v.f=f; unsigned u=v.u; return (u16)((u + 0x7fffu + ((u>>16)&1u))>>16); }

// ---------------- workspace layout (bytes) ----------------
constexpr size_t SZ_DD = (size_t)1024*1024*2;
constexpr size_t OFF_WQ=0;
constexpr size_t OFF_WK=OFF_WQ+SZ_DD;
constexpr size_t OFF_WV=OFF_WK+SZ_DD;
constexpr size_t OFF_WO=OFF_WV+SZ_DD;
constexpr size_t OFF_CAWQ=OFF_WO+SZ_DD;
constexpr size_t OFF_CAWO=OFF_CAWQ+SZ_DD;
constexpr size_t OFF_FF1=OFF_CAWO+SZ_DD;                    // 2048x1024 bf16
constexpr size_t OFF_FF2=OFF_FF1+(size_t)2048*1024*2;       // 1024x2048 bf16
constexpr size_t OFF_MB =OFF_FF2+(size_t)2048*1024*2;       // 1024x1024 bf16 (Wvm@Wvr)
constexpr size_t OFF_WVR=OFF_MB+SZ_DD;                      // 1404x1024 bf16
constexpr size_t OFF_WKP=OFF_WVR+(size_t)1404*1024*2;       // 1024x768 bf16
constexpr size_t OFF_WVP=OFF_WKP+(size_t)1024*768*2;
constexpr size_t OFF_WAFT=OFF_WVP+(size_t)1024*768*2;       // 768x1024 bf16 (W_af^T)
constexpr size_t OFF_WVRT=OFF_WAFT+(size_t)768*1024*2;      // 1024x1408 bf16 (Wvr^T padded)
constexpr size_t OFF_PE  =OFF_WVRT+(size_t)1024*1408*2;     // 25x1024 f32
constexpr size_t OFF_BKP =OFF_PE+25*1024*4;                 // 1024 f32
constexpr size_t OFF_BVP =OFF_BKP+4096;
constexpr size_t OFF_BCOMB=OFF_BVP+4096;
constexpr size_t OFF_MEMK=OFF_BCOMB+4096;                   // 16x1200x1024 bf16
constexpr size_t OFF_MEMV=OFF_MEMK+(size_t)16*1200*1024*2;
constexpr size_t OFF_KC  =OFF_MEMV+(size_t)16*1200*1024*2;  // 600x16x1024 bf16
constexpr size_t OFF_VC  =OFF_KC+(size_t)600*16*1024*2;
constexpr size_t OFF_U3S =OFF_VC+(size_t)600*16*1024*2;     // 600x16x1024 bf16
constexpr size_t OFF_ST3 =OFF_U3S+(size_t)600*16*1024*2;    // 600x16x2 f32
constexpr size_t OFF_EMB =OFF_ST3+600*32*4;                 // 16x1024 bf16
constexpr size_t OFF_QB  =OFF_EMB+32768;
constexpr size_t OFF_SC  =OFF_QB+32768;                     // 16x4x608 f32
constexpr size_t OFF_SA  =OFF_SC+(size_t)16*4*608*4;
constexpr size_t OFF_U1  =OFF_SA+32768;
constexpr size_t OFF_ST1 =OFF_U1+32768;                     // 32 f32
constexpr size_t OFF_Q2  =OFF_ST1+256;
constexpr size_t OFF_CA  =OFF_Q2+32768;
constexpr size_t OFF_U2  =OFF_CA+32768;
constexpr size_t OFF_ST2 =OFF_U2+32768;
constexpr size_t OFF_HH  =OFF_ST2+256;                      // 16x2048 bf16
constexpr size_t OFF_LOSS=OFF_HH+65536;
constexpr size_t OFF_BAR =OFF_LOSS+256;
constexpr size_t WS_NEED =OFF_BAR+256;

// ---------------- shared helpers ----------------
DEV float brmax(float v, float* R){
  #pragma unroll
  for(int o=32;o>0;o>>=1) v = fmaxf(v, __shfl_down(v,o));
  if ((threadIdx.x&63)==0) R[576+(threadIdx.x>>6)] = v;
  __syncthreads();
  v = fmaxf(fmaxf(R[576],R[577]), fmaxf(R[578],R[579]));
  __syncthreads();
  return v;
}
DEV float brsum(float v, float* R){
  #pragma unroll
  for(int o=32;o>0;o>>=1) v += __shfl_down(v,o);
  if ((threadIdx.x&63)==0) R[580+(threadIdx.x>>6)] = v;
  __syncthreads();
  v = (R[580]+R[581])+(R[582]+R[583]);
  __syncthreads();
  return v;
}

// one 16x16 output tile, A staged in LDS (bf16, stride lds_stride u16),
// W row-major [outcol][wstride] bf16, contraction over Kext.
// 4 waves split K, partials reduced through FB. returns value for thread(row=tid>>4,col=tid&15).
DEV float gemm_tile16(const u16* SLu, int lds_stride, const u16* W, int Kext, int wstride, int colbase, float* FB){
  int tid=threadIdx.x, wv=tid>>6, ln=tid&63;
  int r=ln&15, kq=ln>>4;
  int kpw=Kext>>2, k0=wv*kpw;
  const u16* ap = SLu + r*lds_stride + k0 + kq*8;
  const u16* bp = W + (size_t)(colbase+r)*wstride + k0 + kq*8;
  f32x4 acc={0.f,0.f,0.f,0.f};
  for(int k=0;k<kpw;k+=32)
    acc = __builtin_amdgcn_mfma_f32_16x16x32_bf16(*(const s16x8*)(ap+k), *(const s16x8*)(bp+k), acc, 0,0,0);
  #pragma unroll
  for(int j=0;j<4;j++) FB[wv*256 + (kq*4+j)*16 + r] = acc[j];
  __syncthreads();
  int row=tid>>4, col=tid&15;
  float s=(FB[row*16+col]+FB[256+row*16+col])+(FB[512+row*16+col]+FB[768+row*16+col]);
  __syncthreads();
  return s;
}

// stage 16 rows x 1024 cols from src (row stride srcstride, col offset c0base) into SL[16][1032]
DEV void stage16_src(const u16* src, int srcstride, int c0base, u16* SL){
  int row=threadIdx.x>>4, c0=(threadIdx.x&15)<<6;
  const u16* s=src+row*srcstride+c0base+c0; u16* d=SL+row*1032+c0;
  #pragma unroll
  for(int c=0;c<64;c+=8) *(s16x8*)(d+c) = *(const s16x8*)(s+c);
  __syncthreads();
}
DEV void stage16(const u16* src, u16* SL){ stage16_src(src, 1024, 0, SL); }

// stage u (16x1024 bf16) applying LayerNorm(g,be); stats in STm/STr.
DEV void stage_ln16(const u16* u, const float* g, const float* be, u16* SL, float* RB, float* STm, float* STr){
  int tid=threadIdx.x; int row=tid>>4, c0=(tid&15)<<6;
  const u16* s = u + row*1024 + c0;
  s16x8 vr[8]; float sum=0.f, sq=0.f;
  #pragma unroll
  for(int c=0;c<8;c++){
    vr[c] = *(const s16x8*)(s + c*8);
    #pragma unroll
    for(int j=0;j<8;j++){ float f=bf2f((u16)vr[c][j]); sum+=f; sq+=f*f; }
  }
  RB[tid]=sum; RB[256+tid]=sq;
  __syncthreads();
  if (tid<16){
    float S=0.f,Q=0.f;
    #pragma unroll
    for(int k=0;k<16;k++){ S+=RB[tid*16+k]; Q+=RB[256+tid*16+k]; }
    float m=S*(1.f/1024.f); float var=Q*(1.f/1024.f)-m*m;
    STm[tid]=m; STr[tid]=rsqrtf(var+1e-5f);
  }
  __syncthreads();
  float m=STm[row], rs=STr[row];
  u16* d = SL + row*1032 + c0;
  #pragma unroll
  for(int c=0;c<8;c++){
    s16x8 o;
    #pragma unroll
    for(int j=0;j<8;j++){ int cc=c0+c*8+j; float f=(bf2f((u16)vr[c][j])-m)*rs*g[cc]+be[cc]; o[j]=(short)f2bf(f); }
    *(s16x8*)(d + c*8) = o;
  }
  __syncthreads();
}

// grid-wide barrier: counter + generation, agent-scope fences.
// Requires all blocks co-resident (grid == 256 blocks, <=64KB LDS -> 1+/CU on 256 CUs).
DEV void gbar(unsigned* bar, unsigned& epoch){
  __builtin_amdgcn_fence(__ATOMIC_RELEASE, "agent");
  __syncthreads();
  if (threadIdx.x == 0){
    unsigned prev = __hip_atomic_fetch_add(&bar[0], 1u, __ATOMIC_RELAXED, __HIP_MEMORY_SCOPE_AGENT);
    if (prev == epoch*256u + 255u){
      __builtin_amdgcn_fence(__ATOMIC_ACQUIRE, "agent");
      __hip_atomic_store(&bar[1], epoch+1u, __ATOMIC_RELEASE, __HIP_MEMORY_SCOPE_AGENT);
    } else {
      while (__hip_atomic_load(&bar[1], __ATOMIC_RELAXED, __HIP_MEMORY_SCOPE_AGENT) < epoch+1u)
        __builtin_amdgcn_s_sleep(2);
    }
  }
  __syncthreads();
  __builtin_amdgcn_fence(__ATOMIC_ACQUIRE, "agent");
  epoch++;
}

// ---------------- prep kernels ----------------
__global__ void __launch_bounds__(256) k_init(const float* b_vm, float* pe, u16* emb, float* loss, unsigned* bar){
  int tid=threadIdx.x;
  if (tid==0){ loss[0]=0.f; bar[0]=0u; bar[1]=0u; }
  for(int idx=tid; idx<16384; idx+=256) emb[idx] = f2bf(b_vm[idx&1023]);
  for(int idx=tid; idx<25600; idx+=256){
    int p_=idx>>10, d_=idx&1023; int m=d_>>1;
    float div = expf(-(float)(2*m) * (9.210340372f/1024.f));
    float a = (float)p_ * div;
    pe[idx] = (d_&1)? cosf(a) : sinf(a);
  }
}

__global__ void __launch_bounds__(256) k_f2bf(const float* s, u16* d, int n){
  int idx=(blockIdx.x*256+threadIdx.x)*8;
  if (idx < n){
    #pragma unroll
    for(int j=0;j<8;j++) d[idx+j]=f2bf(s[idx+j]);
  }
}

// dst[j*ldd+rr] = (rr<R) ? src[rr*C+j] : 0 ;  j<C, rr<ldd
__global__ void __launch_bounds__(256) k_tr(const float* src, int R, int C, u16* dst, int ldd){
  __shared__ float TL[32][33];
  int cb=(C+31)/32;
  int bj=blockIdx.x%cb, br=blockIdx.x/cb;
  int j0=bj*32, r0=br*32;
  int lj=threadIdx.x&31, lr=threadIdx.x>>5;
  #pragma unroll
  for(int p=0;p<4;p++){ int rr=r0+lr+p*8, jj=j0+lj;
    TL[lr+p*8][lj] = (rr<R && jj<C)? src[(size_t)rr*C+jj] : 0.f; }
  __syncthreads();
  #pragma unroll
  for(int p=0;p<4;p++){ int jj=j0+lr+p*8, rr=r0+lj;
    if (jj<C && rr<ldd) dst[(size_t)jj*ldd+rr] = f2bf(TL[lj][lr+p*8]); }
}

// out[(mt*16+row)*ldo + nt*16+col] = sum_k A[row_g][k]*Bw[col_g][k]  (A f32, Bw bf16 row-major Kpad)
__global__ void __launch_bounds__(256) k_gemm_pre(const float* A, int lda, int Kreal, int Kpad,
                                                  const u16* Bw, u16* out, int ldo, int Ntiles){
  __shared__ u16 SL[16*1416];
  __shared__ float FB[1024];
  int bx=blockIdx.x; int mt=bx/Ntiles, nt=bx%Ntiles;
  int tid=threadIdx.x;
  int cpt = Kpad>>4;
  { int row=tid>>4, c0=(tid&15)*cpt;
    const float* s=A + (size_t)(mt*16+row)*lda;
    u16* d=SL + row*(Kpad+8);
    for(int c=0;c<cpt;c++){ int k=c0+c; d[k] = (k<Kreal)? f2bf(s[k]) : (u16)0; }
    __syncthreads();
  }
  float v = gemm_tile16(SL, Kpad+8, Bw, Kpad, Kpad, nt*16, FB);
  int row=tid>>4, col=tid&15;
  out[(size_t)(mt*16+row)*ldo + nt*16+col] = f2bf(v);
}

__global__ void __launch_bounds__(256) k_bvec(const float* caWk, const float* ca_bk, const float* b_af,
                                              const float* caWv, const float* ca_bv,
                                              const float* Wvm, const float* b_vr, const float* b_vm,
                                              float* bkp, float* bvp, float* bcomb){
  __shared__ float VB[1408];
  int seg=blockIdx.x>>2, ch=blockIdx.x&3; int o=ch*256+threadIdx.x;
  const float* vec = (seg==2)? b_vr : b_af; int K = (seg==2)?1404:1024;
  for(int k=threadIdx.x;k<K;k+=256) VB[k]=vec[k];
  __syncthreads();
  const float* Arow = (seg==0)? caWk+(size_t)o*1024 : (seg==1)? caWv+(size_t)o*1024 : Wvm+(size_t)o*1404;
  float s=0.f;
  for(int k=0;k<K;k++) s += Arow[k]*VB[k];
  if(seg==0) bkp[o]=s+ca_bk[o]; else if(seg==1) bvp[o]=s+ca_bv[o]; else bcomb[o]=s+b_vm[o];
}

// mem_k/mem_v = audio @ Wk'/Wv'^T + bias   (grid 1200 x 8, 128 cols per wg)
__global__ void __launch_bounds__(256) k_mem(const float* audio, const u16* wkp, const u16* wvp,
                                             const float* bkp, const float* bvp, u16* memk, u16* memv){
  __shared__ u16 SL[16*776];
  int bx=blockIdx.x; int mt=bx>>3, cbk=bx&7;
  int tid=threadIdx.x, wv=tid>>6, ln=tid&63;
  { int row=tid>>4, c0=(tid&15)*48;
    const float* s = audio + (size_t)(mt*16+row)*768 + c0;
    u16* d = SL + row*776 + c0;
    #pragma unroll
    for(int c=0;c<48;c+=8){ s16x8 o;
      #pragma unroll
      for(int j=0;j<8;j++) o[j]=(short)f2bf(s[c+j]);
      *(s16x8*)(d+c)=o; }
    __syncthreads();
  }
  int r=ln&15, kq=ln>>4;
  const u16* ap = SL + r*776 + kq*8;
  for(int rep=0;rep<2;rep++){
    int colb = cbk*128 + wv*32 + rep*16;
    for(int mat=0;mat<2;mat++){
      const u16* W = mat? wvp : wkp;
      const u16* bp = W + (size_t)(colb+r)*768 + kq*8;
      f32x4 acc={0.f,0.f,0.f,0.f};
      for(int k=0;k<768;k+=32)
        acc = __builtin_amdgcn_mfma_f32_16x16x32_bf16(*(const s16x8*)(ap+k), *(const s16x8*)(bp+k), acc, 0,0,0);
      const float* bias = mat? bvp:bkp; u16* out = mat? memv:memk;
      int o = colb + r;
      float bo = bias[o];
      #pragma unroll
      for(int j=0;j<4;j++){ int row_=kq*4+j;
        out[(size_t)(mt*16+row_)*1024 + o] = f2bf(acc[j] + bo); }
    }
  }
}

// ---------------- main sequential loop (plain launch, 256 co-resident blocks) ----------------
struct LoopArgs {
  const float *sa_bq,*sa_bk,*sa_bv,*sa_bo,*ca_bq,*ca_bo,*b_ff1,*b_ff2;
  const float *g1,*be1,*g2,*be2,*g3,*be3;
  char* ws;
};

__global__ void __launch_bounds__(256) k_loop(LoopArgs A){
  __shared__ u16 SL[16*1032];        // 33 KB
  __shared__ float FB[1024];         // 4 KB
  __shared__ float PL[608];
  __shared__ float RB[640];
  __shared__ float STm[16], STr[16]; // total ~42 KB LDS

  char* ws = A.ws;
  const u16* wq   =(const u16*)(ws+OFF_WQ);
  const u16* wk   =(const u16*)(ws+OFF_WK);
  const u16* wv_  =(const u16*)(ws+OFF_WV);
  const u16* wo   =(const u16*)(ws+OFF_WO);
  const u16* cawq =(const u16*)(ws+OFF_CAWQ);
  const u16* cawo =(const u16*)(ws+OFF_CAWO);
  const u16* ff1  =(const u16*)(ws+OFF_FF1);
  const u16* ff2  =(const u16*)(ws+OFF_FF2);
  const u16* mb   =(const u16*)(ws+OFF_MB);
  const float* pe =(const float*)(ws+OFF_PE);
  const float* bcomb=(const float*)(ws+OFF_BCOMB);
  const u16* memk =(const u16*)(ws+OFF_MEMK);
  const u16* memv =(const u16*)(ws+OFF_MEMV);
  u16* kc =(u16*)(ws+OFF_KC);
  u16* vc =(u16*)(ws+OFF_VC);
  u16* u3s=(u16*)(ws+OFF_U3S);
  float* st3=(float*)(ws+OFF_ST3);
  u16* emb=(u16*)(ws+OFF_EMB);
  u16* qb =(u16*)(ws+OFF_QB);
  float* scoresb=(float*)(ws+OFF_SC);
  u16* sab=(u16*)(ws+OFF_SA);
  u16* u1 =(u16*)(ws+OFF_U1);
  float* st1=(float*)(ws+OFF_ST1);
  u16* q2b=(u16*)(ws+OFF_Q2);
  u16* cab=(u16*)(ws+OFF_CA);
  u16* u2 =(u16*)(ws+OFF_U2);
  float* st2=(float*)(ws+OFF_ST2);
  u16* hh =(u16*)(ws+OFF_HH);
  unsigned* bar=(unsigned*)(ws+OFF_BAR);

  unsigned epoch = 0;
  int wg = blockIdx.x, tid = threadIdx.x;
  int row = tid>>4, lo = tid&15;

  #pragma unroll 1
  for (int i=0;i<600;i++){
    int ip = i%25;

    // ---- phase A: x = emb + pe ; q/k/v projections ----
    if (wg < 192){
      { int c0 = lo<<6;
        const u16* s = emb + row*1024 + c0;
        const float* pp = pe + ip*1024 + c0;
        u16* d = SL + row*1032 + c0;
        #pragma unroll
        for(int c=0;c<64;c+=8){ s16x8 e = *(const s16x8*)(s+c); s16x8 o;
          #pragma unroll
          for(int j=0;j<8;j++) o[j] = (short)f2bf(bf2f((u16)e[j]) + pp[c+j]);
          *(s16x8*)(d+c) = o; }
        __syncthreads();
      }
      const u16* W; const float* bias; u16* outp;
      if (wg<64){ W=wq;  bias=A.sa_bq; outp=qb; }
      else if (wg<128){ W=wk; bias=A.sa_bk; outp=kc + i*16384; }
      else { W=wv_; bias=A.sa_bv; outp=vc + i*16384; }
      int colb = (wg&63)<<4;
      float v = gemm_tile16(SL,1032,W,1024,1024,colb,FB);
      int o = colb + lo;
      outp[row*1024 + o] = f2bf(v + bias[o]);
    }
    gbar(bar, epoch);

    // ---- phase B1: self-attn scores ----
    { int b=wg>>4, h=(wg>>2)&3, tq=wg&3, cnt=i+1;
      RB[tid] = bf2f(qb[b*1024 + h*256 + tid]);
      __syncthreads();
      int t0=(tq*cnt)>>2, t1=((tq+1)*cnt)>>2;
      float sl = 1.0f/(float)(4<<(2*h));
      for(int t=t0+tid; t<t1; t+=256){
        const u16* kr = kc + (t*16+b)*1024 + h*256;
        float s=0.f;
        #pragma unroll
        for(int c=0;c<256;c+=8){ s16x8 kv8 = *(const s16x8*)(kr+c);
          #pragma unroll
          for(int j=0;j<8;j++) s += RB[c+j]*bf2f((u16)kv8[j]); }
        s = s*0.0625f - sl*(float)((i-t)/25);
        scoresb[(b*4+h)*608 + t] = s;
      }
      __syncthreads();
    }
    gbar(bar, epoch);

    // ---- phase B2: softmax + V ----
    { int b=wg>>4, h=(wg>>2)&3, dq=wg&3, cnt=i+1;
      float* sc = scoresb + (b*4+h)*608;
      float mx = -1e30f;
      for(int t=tid;t<cnt;t+=256){ float s=sc[t]; PL[t]=s; mx=fmaxf(mx,s); }
      mx = brmax(mx, RB);
      float ls=0.f;
      for(int t=tid;t<cnt;t+=256){ float e=__expf(PL[t]-mx); PL[t]=e; ls+=e; }
      float l = brsum(ls, RB);
      float rl = 1.0f/l;
      int d = tid&63, toff = tid>>6;
      const u16* vcb = vc + b*1024 + h*256 + dq*64 + d;
      float acc=0.f;
      for(int t=toff;t<cnt;t+=4) acc += PL[t]*bf2f(vcb[t*16384]);
      RB[tid]=acc;
      __syncthreads();
      if (tid<64){
        float s=(RB[tid]+RB[tid+64])+(RB[tid+128]+RB[tid+192]);
        sab[b*1024 + h*256 + dq*64 + tid] = f2bf(s*rl);
      }
      __syncthreads();
    }
    gbar(bar, epoch);

    // ---- phase C: u1 = x + sa@Wo^T + bo ----
    if (wg>=192){
      stage16(sab, SL);
      int colb = (wg-192)<<4;
      float v = gemm_tile16(SL,1032,wo,1024,1024,colb,FB);
      int o = colb+lo;
      float x = bf2f(emb[row*1024+o]) + pe[ip*1024+o];
      u1[row*1024+o] = f2bf(x + v + A.sa_bo[o]);
    }
    gbar(bar, epoch);

    // ---- phase D: q2 = LN1(u1)@caWq^T + bq ----
    if (wg<64){
      stage_ln16(u1, A.g1, A.be1, SL, RB, STm, STr);
      int colb = wg<<4;
      float v = gemm_tile16(SL,1032,cawq,1024,1024,colb,FB);
      int o=colb+lo;
      q2b[row*1024+o] = f2bf(v + A.ca_bq[o]);
      if (wg==0 && tid<16){ st1[tid*2]=STm[tid]; st1[tid*2+1]=STr[tid]; }
    }
    gbar(bar, epoch);

    // ---- phase E: windowed cross-attn -> ca ----
    if (wg<64){
      int b=wg>>2, h=wg&3;
      PL[tid] = bf2f(q2b[b*1024 + h*256 + tid]);
      __syncthreads();
      int s0 = 2*i-6; if(s0<0)s0=0;
      int s1 = 2*i+2; if(s1>1200)s1=1200;
      int ns = s1-s0;
      int wvv = tid>>6;
      for(int si=0;si<ns;si++){
        float ppv = PL[tid]*bf2f(memk[(size_t)(b*1200+s0+si)*1024 + h*256 + tid]);
        #pragma unroll
        for(int o2=32;o2>0;o2>>=1) ppv += __shfl_down(ppv,o2);
        if ((tid&63)==0) RB[si*4+wvv] = ppv;
      }
      __syncthreads();
      if (tid<8 && tid<ns) RB[64+tid] = (RB[tid*4]+RB[tid*4+1]+RB[tid*4+2]+RB[tid*4+3])*0.0625f;
      __syncthreads();
      float mx=-1e30f;
      for(int si=0;si<ns;si++) mx=fmaxf(mx,RB[64+si]);
      float l=0.f, acc=0.f;
      for(int si=0;si<ns;si++){
        float e=__expf(RB[64+si]-mx); l+=e;
        acc += e*bf2f(memv[(size_t)(b*1200+s0+si)*1024 + h*256 + tid]);
      }
      cab[b*1024+h*256+tid] = f2bf(acc/l);
      __syncthreads();
    }
    gbar(bar, epoch);

    // ---- phase F: u2 = x1 + ca@caWo^T + bo2 ----
    if (wg>=64 && wg<128){
      stage16(cab, SL);
      int colb = (wg-64)<<4;
      float v = gemm_tile16(SL,1032,cawo,1024,1024,colb,FB);
      int o=colb+lo;
      float m1=st1[row*2], r1=st1[row*2+1];
      float x1 = (bf2f(u1[row*1024+o])-m1)*r1*A.g1[o] + A.be1[o];
      u2[row*1024+o] = f2bf(x1 + v + A.ca_bo[o]);
    }
    gbar(bar, epoch);

    // ---- phase G: hh = relu(LN2(u2)@FF1^T + b1) ----
    if (wg<128){
      stage_ln16(u2, A.g2, A.be2, SL, RB, STm, STr);
      int colb = wg<<4;
      float v = gemm_tile16(SL,1032,ff1,1024,1024,colb,FB);
      int o=colb+lo;
      hh[row*2048+o] = f2bf(fmaxf(v + A.b_ff1[o], 0.f));
      if (wg==0 && tid<16){ st2[tid*2]=STm[tid]; st2[tid*2+1]=STr[tid]; }
    }
    gbar(bar, epoch);

    // ---- phase H: u3 = x2 + hh@FF2^T + b2  (K=2048 split in two 1024 chunks) ----
    if (wg>=128 && wg<192){
      int colb = (wg-128)<<4;
      stage16_src(hh, 2048, 0, SL);
      float v = gemm_tile16(SL,1032,ff2,1024,2048,colb,FB);
      stage16_src(hh, 2048, 1024, SL);
      v += gemm_tile16(SL,1032,ff2+1024,1024,2048,colb,FB);
      int o=colb+lo;
      float m2=st2[row*2], r2=st2[row*2+1];
      float x2 = (bf2f(u2[row*1024+o])-m2)*r2*A.g2[o] + A.be2[o];
      u3s[(i*16+row)*1024+o] = f2bf(x2 + v + A.b_ff2[o]);
    }
    gbar(bar, epoch);

    // ---- phase I: emb = LN3(u3)@M^T + bcomb ----
    if (wg>=192){
      stage_ln16(u3s + i*16384, A.g3, A.be3, SL, RB, STm, STr);
      int colb = (wg-192)<<4;
      float v = gemm_tile16(SL,1032,mb,1024,1024,colb,FB);
      int o=colb+lo;
      emb[row*1024+o] = f2bf(v + bcomb[o]);
      if (wg==192 && tid<16){ st3[i*32+tid*2]=STm[tid]; st3[i*32+tid*2+1]=STr[tid]; }
    }
    gbar(bar, epoch);
  }
}

// ---------------- deferred loss ----------------
__global__ void __launch_bounds__(256) k_loss(const u16* u3s, const float* st3, const u16* wvr,
                                              const float* bvr, const float* g3, const float* be3,
                                              const float* vert, float* loss){
  __shared__ u16 SL[16*1032];
  __shared__ float R[64];
  int bx=blockIdx.x; int ib=bx/11, cb=bx%11;
  int tid=threadIdx.x, wvv=tid>>6, ln=tid&63;
  int r=ln&15, kq=ln>>4;
  float lsum=0.f;
  for(int ii=0;ii<8;ii++){
    int i=ib*8+ii;
    { int row=tid>>4, c0=(tid&15)<<6;
      float m=st3[i*32+row*2], rs=st3[i*32+row*2+1];
      const u16* s=u3s + (size_t)(i*16+row)*1024 + c0;
      u16* d=SL + row*1032 + c0;
      #pragma unroll
      for(int c=0;c<64;c+=8){ s16x8 v=*(const s16x8*)(s+c); s16x8 o;
        #pragma unroll
        for(int j=0;j<8;j++){ int cc=c0+c+j; o[j]=(short)f2bf((bf2f((u16)v[j])-m)*rs*g3[cc]+be3[cc]); }
        *(s16x8*)(d+c)=o; }
      __syncthreads();
    }
    const u16* ap = SL + r*1032 + kq*8;
    for(int rep=0;rep<2;rep++){
      int colb = cb*128 + wvv*32 + rep*16;
      int o_r = colb + r; bool ok = o_r < 1404;
      const u16* bp = wvr + (size_t)(ok? o_r:0)*1024 + kq*8;
      f32x4 acc={0.f,0.f,0.f,0.f};
      for(int k=0;k<1024;k+=32)
        acc = __builtin_amdgcn_mfma_f32_16x16x32_bf16(*(const s16x8*)(ap+k), *(const s16x8*)(bp+k), acc, 0,0,0);
      if (ok){
        float bo = bvr[o_r];
        #pragma unroll
        for(int j=0;j<4;j++){
          int b_=kq*4+j;
          float ov = acc[j] + bo;
          float vt = vert[(size_t)(b_*600 + i)*1404 + o_r];
          float dd = ov - vt; lsum += dd*dd;
        }
      }
    }
    __syncthreads();
  }
  #pragma unroll
  for(int o=32;o>0;o>>=1) lsum += __shfl_down(lsum,o);
  if (ln==0) R[wvv]=lsum;
  __syncthreads();
  if (tid==0) atomicAdd(loss, (R[0]+R[1])+(R[2]+R[3]));
}

__global__ void k_fin(const float* loss, float* dout){
  if (threadIdx.x==0) dout[0] = loss[0] * (1.f/13478400.f);   // / (16*600*1404)
}

// ---------------- host ----------------
extern "C" void kernel_launch(void* const* d_in, const int* in_sizes, int n_in,
                              void* d_out, int out_size, void* d_ws, size_t ws_size,
                              hipStream_t stream){
  char* ws = (char*)d_ws;
  if (ws_size < WS_NEED){ hipMemsetAsync(d_out, 0, 4, stream); return; }

  const float* audio=(const float*)d_in[0];
  const float* vert =(const float*)d_in[1];
  const float* W_af =(const float*)d_in[2];
  const float* b_af =(const float*)d_in[3];
  const float* saWq =(const float*)d_in[4];  const float* sa_bq=(const float*)d_in[5];
  const float* saWk =(const float*)d_in[6];  const float* sa_bk=(const float*)d_in[7];
  const float* saWv =(const float*)d_in[8];  const float* sa_bv=(const float*)d_in[9];
  const float* saWo =(const float*)d_in[10]; const float* sa_bo=(const float*)d_in[11];
  const float* caWq =(const float*)d_in[12]; const float* ca_bq=(const float*)d_in[13];
  const float* caWk =(const float*)d_in[14]; const float* ca_bk=(const float*)d_in[15];
  const float* caWv =(const float*)d_in[16]; const float* ca_bv=(const float*)d_in[17];
  const float* caWo =(const float*)d_in[18]; const float* ca_bo=(const float*)d_in[19];
  const float* g1=(const float*)d_in[20]; const float* be1=(const float*)d_in[21];
  const float* g2=(const float*)d_in[22]; const float* be2=(const float*)d_in[23];
  const float* g3=(const float*)d_in[24]; const float* be3=(const float*)d_in[25];
  const float* Wff1=(const float*)d_in[26]; const float* b_ff1=(const float*)d_in[27];
  const float* Wff2=(const float*)d_in[28]; const float* b_ff2=(const float*)d_in[29];
  const float* Wvm=(const float*)d_in[30];  const float* b_vm=(const float*)d_in[31];
  const float* Wvr=(const float*)d_in[32];  const float* b_vr=(const float*)d_in[33];

  k_init<<<1,256,0,stream>>>(b_vm, (float*)(ws+OFF_PE), (u16*)(ws+OFF_EMB), (float*)(ws+OFF_LOSS), (unsigned*)(ws+OFF_BAR));

  k_f2bf<<<512,256,0,stream>>>(saWq,(u16*)(ws+OFF_WQ),1048576);
  k_f2bf<<<512,256,0,stream>>>(saWk,(u16*)(ws+OFF_WK),1048576);
  k_f2bf<<<512,256,0,stream>>>(saWv,(u16*)(ws+OFF_WV),1048576);
  k_f2bf<<<512,256,0,stream>>>(saWo,(u16*)(ws+OFF_WO),1048576);
  k_f2bf<<<512,256,0,stream>>>(caWq,(u16*)(ws+OFF_CAWQ),1048576);
  k_f2bf<<<512,256,0,stream>>>(caWo,(u16*)(ws+OFF_CAWO),1048576);
  k_f2bf<<<1024,256,0,stream>>>(Wff1,(u16*)(ws+OFF_FF1),2097152);
  k_f2bf<<<1024,256,0,stream>>>(Wff2,(u16*)(ws+OFF_FF2),2097152);
  k_f2bf<<<702,256,0,stream>>>(Wvr,(u16*)(ws+OFF_WVR),1437696);

  k_tr<<<24*32,256,0,stream>>>(W_af, 1024, 768, (u16*)(ws+OFF_WAFT), 1024);
  k_tr<<<32*44,256,0,stream>>>(Wvr, 1404, 1024, (u16*)(ws+OFF_WVRT), 1408);

  k_gemm_pre<<<64*48,256,0,stream>>>(caWk, 1024, 1024, 1024, (const u16*)(ws+OFF_WAFT), (u16*)(ws+OFF_WKP), 768, 48);
  k_gemm_pre<<<64*48,256,0,stream>>>(caWv, 1024, 1024, 1024, (const u16*)(ws+OFF_WAFT), (u16*)(ws+OFF_WVP), 768, 48);
  k_gemm_pre<<<64*64,256,0,stream>>>(Wvm, 1404, 1404, 1408, (const u16*)(ws+OFF_WVRT), (u16*)(ws+OFF_MB), 1024, 64);

  k_bvec<<<12,256,0,stream>>>(caWk, ca_bk, b_af, caWv, ca_bv, Wvm, b_vr, b_vm,
                              (float*)(ws+OFF_BKP),(float*)(ws+OFF_BVP),(float*)(ws+OFF_BCOMB));

  k_mem<<<9600,256,0,stream>>>(audio, (const u16*)(ws+OFF_WKP),(const u16*)(ws+OFF_WVP),
                               (const float*)(ws+OFF_BKP),(const float*)(ws+OFF_BVP),
                               (u16*)(ws+OFF_MEMK),(u16*)(ws+OFF_MEMV));

  LoopArgs la{ sa_bq, sa_bk, sa_bv, sa_bo, ca_bq, ca_bo, b_ff1, b_ff2,
               g1, be1, g2, be2, g3, be3, ws };
  k_loop<<<256,256,0,stream>>>(la);

  k_loss<<<825,256,0,stream>>>((const u16*)(ws+OFF_U3S),(const float*)(ws+OFF_ST3),
                               (const u16*)(ws+OFF_WVR), b_vr, g3, be3, vert, (float*)(ws+OFF_LOSS));
  k_fin<<<1,64,0,stream>>>((const float*)(ws+OFF_LOSS), (float*)d_out);
}

// Round 3
// 136784.607 us; speedup vs baseline: 1.4806x; 1.4806x over previous
//
#include <hip/hip_runtime.h>

typedef unsigned short u16;
typedef short s16x8 __attribute__((ext_vector_type(8)));
typedef float f32x4 __attribute__((ext_vector_type(4)));

#define DEV static __device__ __forceinline__

DEV float bf2f(u16 h){ union{unsigned u;float f;} v; v.u=((unsigned)h)<<16; return v.f; }
DEV u16 f2bf(float f){ union{float f;unsigned u;} v; v.f=f; unsigned u=v.u; return (u16)((u + 0x7fffu + ((u>>16)&1u))>>16); }

// ---------------- workspace layout (bytes) ----------------
constexpr size_t SZ_DD = (size_t)1024*1024*2;
constexpr size_t OFF_WQ=0;
constexpr size_t OFF_WK=OFF_WQ+SZ_DD;
constexpr size_t OFF_WV=OFF_WK+SZ_DD;
constexpr size_t OFF_WO=OFF_WV+SZ_DD;
constexpr size_t OFF_CAWQ=OFF_WO+SZ_DD;
constexpr size_t OFF_CAWO=OFF_CAWQ+SZ_DD;
constexpr size_t OFF_FF1=OFF_CAWO+SZ_DD;                    // 2048x1024 bf16
constexpr size_t OFF_FF2=OFF_FF1+(size_t)2048*1024*2;       // 2048-K x 1024 rows bf16 (row stride 2048)
constexpr size_t OFF_MB =OFF_FF2+(size_t)2048*1024*2;       // 1024x1024 bf16 (Wvm@Wvr)
constexpr size_t OFF_WVR=OFF_MB+SZ_DD;                      // 1404x1024 bf16
constexpr size_t OFF_WKP=OFF_WVR+(size_t)1404*1024*2;       // 1024x768 bf16
constexpr size_t OFF_WVP=OFF_WKP+(size_t)1024*768*2;
constexpr size_t OFF_WAFT=OFF_WVP+(size_t)1024*768*2;       // 768x1024 bf16 (W_af^T)
constexpr size_t OFF_WVRT=OFF_WAFT+(size_t)768*1024*2;      // 1024x1408 bf16 (Wvr^T padded)
constexpr size_t OFF_PE  =OFF_WVRT+(size_t)1024*1408*2;     // 25x1024 f32
constexpr size_t OFF_BKP =OFF_PE+25*1024*4;                 // 1024 f32
constexpr size_t OFF_BVP =OFF_BKP+4096;
constexpr size_t OFF_BCOMB=OFF_BVP+4096;
constexpr size_t OFF_MEMK=OFF_BCOMB+4096;                   // oct layout [16][4][32][1200][8] bf16
constexpr size_t OFF_MEMV=OFF_MEMK+(size_t)16*1200*1024*2;  // normal [b*1200+s][1024]
constexpr size_t OFF_KC  =OFF_MEMV+(size_t)16*1200*1024*2;  // K oct [16][4][32][600][8] bf16
constexpr size_t OFF_VC  =OFF_KC+(size_t)600*16*1024*2;     // V oct
constexpr size_t OFF_U3S =OFF_VC+(size_t)600*16*1024*2;     // 600x16x1024 bf16
constexpr size_t OFF_ST3 =OFF_U3S+(size_t)600*16*1024*2;    // 600x16x2 f32
constexpr size_t OFF_EMB =OFF_ST3+600*32*4;                 // 16x1024 bf16
constexpr size_t OFF_QB  =OFF_EMB+32768;
constexpr size_t OFF_SC  =OFF_QB+32768;                     // (unused, reserved)
constexpr size_t OFF_SA  =OFF_SC+(size_t)16*4*608*4;
constexpr size_t OFF_U1  =OFF_SA+32768;
constexpr size_t OFF_ST1 =OFF_U1+32768;                     // 32 f32
constexpr size_t OFF_Q2  =OFF_ST1+256;
constexpr size_t OFF_CA  =OFF_Q2+32768;
constexpr size_t OFF_U2  =OFF_CA+32768;
constexpr size_t OFF_ST2 =OFF_U2+32768;
constexpr size_t OFF_HH  =OFF_ST2+256;                      // 16x2048 bf16
constexpr size_t OFF_LOSS=OFF_HH+65536;
constexpr size_t OFF_BAR =OFF_LOSS+256;                     // 18 x 256B barrier lines
constexpr size_t WS_NEED =OFF_BAR+8192;

// ---------------- shared helpers ----------------
DEV float brmax(float v, float* R){
  #pragma unroll
  for(int o=32;o>0;o>>=1) v = fmaxf(v, __shfl_down(v,o));
  if ((threadIdx.x&63)==0) R[576+(threadIdx.x>>6)] = v;
  __syncthreads();
  v = fmaxf(fmaxf(R[576],R[577]), fmaxf(R[578],R[579]));
  __syncthreads();
  return v;
}
DEV float brsum(float v, float* R){
  #pragma unroll
  for(int o=32;o>0;o>>=1) v += __shfl_down(v,o);
  if ((threadIdx.x&63)==0) R[580+(threadIdx.x>>6)] = v;
  __syncthreads();
  v = (R[580]+R[581])+(R[582]+R[583]);
  __syncthreads();
  return v;
}

// GEMM 16x16 tile: A from SL (stride lds_stride), B from swizzled LDS weight slot
// (16 rows x 1024 K, u16 idx = r*1024 + (k ^ ((r&7)<<3)) ). K=1024 fixed, 4 waves split K.
DEV float gemm_w(const u16* SLu, int lds_stride, const u16* slot, float* FB){
  int tid=threadIdx.x, wv=tid>>6, ln=tid&63;
  int r=ln&15, kq=ln>>4;
  int k0=wv*256 + kq*8;
  const u16* ap = SLu + r*lds_stride + k0;
  int sw=(r&7)<<3;
  const u16* bp = slot + r*1024;
  f32x4 acc={0.f,0.f,0.f,0.f};
  #pragma unroll
  for(int k=0;k<1024;k+=128)
    acc = __builtin_amdgcn_mfma_f32_16x16x32_bf16(*(const s16x8*)(ap+(k>>2)),
                                                  *(const s16x8*)(bp + (((k0+(k>>2)))^sw)), acc, 0,0,0);
  #pragma unroll
  for(int j=0;j<4;j++) FB[wv*256 + (kq*4+j)*16 + r] = acc[j];
  __syncthreads();
  int row=tid>>4, col=tid&15;
  float s=(FB[row*16+col]+FB[256+row*16+col])+(FB[512+row*16+col]+FB[768+row*16+col]);
  __syncthreads();
  return s;
}

// copy one 16x1024 bf16 weight tile (global, row stride rstride) into swizzled LDS slot
DEV void copy_slot(const u16* src, int rstride, u16* dst){
  int row=threadIdx.x>>4, k0=(threadIdx.x&15)<<6;
  int sw=(row&7)<<3;
  const u16* s = src + (size_t)row*rstride + k0;
  u16* d = dst + row*1024;
  #pragma unroll
  for(int c=0;c<64;c+=8)
    *(s16x8*)(d + (((k0+c))^sw)) = *(const s16x8*)(s+c);
}

// stage 16 rows x 1024 cols from src (row stride srcstride, col offset c0base) into SL[16][1032]
DEV void stage16_src(const u16* src, int srcstride, int c0base, u16* SL){
  int row=threadIdx.x>>4, c0=(threadIdx.x&15)<<6;
  const u16* s=src+row*srcstride+c0base+c0; u16* d=SL+row*1032+c0;
  #pragma unroll
  for(int c=0;c<64;c+=8) *(s16x8*)(d+c) = *(const s16x8*)(s+c);
  __syncthreads();
}
DEV void stage16(const u16* src, u16* SL){ stage16_src(src, 1024, 0, SL); }

// stage u (16x1024 bf16) applying LayerNorm(g,be); stats in STm/STr.
DEV void stage_ln16(const u16* u, const float* g, const float* be, u16* SL, float* RB, float* STm, float* STr){
  int tid=threadIdx.x; int row=tid>>4, c0=(tid&15)<<6;
  const u16* s = u + row*1024 + c0;
  s16x8 vr[8]; float sum=0.f, sq=0.f;
  #pragma unroll
  for(int c=0;c<8;c++){
    vr[c] = *(const s16x8*)(s + c*8);
    #pragma unroll
    for(int j=0;j<8;j++){ float f=bf2f((u16)vr[c][j]); sum+=f; sq+=f*f; }
  }
  RB[tid]=sum; RB[256+tid]=sq;
  __syncthreads();
  if (tid<16){
    float S=0.f,Q=0.f;
    #pragma unroll
    for(int k=0;k<16;k++){ S+=RB[tid*16+k]; Q+=RB[256+tid*16+k]; }
    float m=S*(1.f/1024.f); float var=Q*(1.f/1024.f)-m*m;
    STm[tid]=m; STr[tid]=rsqrtf(var+1e-5f);
  }
  __syncthreads();
  float m=STm[row], rs=STr[row];
  u16* d = SL + row*1032 + c0;
  #pragma unroll
  for(int c=0;c<8;c++){
    s16x8 o;
    #pragma unroll
    for(int j=0;j<8;j++){ int cc=c0+c*8+j; float f=(bf2f((u16)vr[c][j])-m)*rs*g[cc]+be[cc]; o[j]=(short)f2bf(f); }
    *(s16x8*)(d + c*8) = o;
  }
  __syncthreads();
}

// grid barrier: hierarchical arrival (16 leaves + root), generation flag, agent fences.
DEV void gbar(char* barb, unsigned& epoch){
  __builtin_amdgcn_fence(__ATOMIC_RELEASE, "agent");
  __syncthreads();
  if (threadIdx.x == 0){
    unsigned* leaf = (unsigned*)(barb + ((blockIdx.x & 15) << 8));
    unsigned* root = (unsigned*)(barb + (16 << 8));
    unsigned* flag = (unsigned*)(barb + (17 << 8));
    unsigned target = epoch + 1u;
    unsigned prev = __hip_atomic_fetch_add(leaf, 1u, __ATOMIC_RELAXED, __HIP_MEMORY_SCOPE_AGENT);
    bool done=false;
    if (prev == epoch*16u + 15u){
      unsigned p2 = __hip_atomic_fetch_add(root, 1u, __ATOMIC_RELAXED, __HIP_MEMORY_SCOPE_AGENT);
      if (p2 == epoch*16u + 15u){
        __hip_atomic_store(flag, target, __ATOMIC_RELEASE, __HIP_MEMORY_SCOPE_AGENT);
        done=true;
      }
    }
    if (!done){
      while (__hip_atomic_load(flag, __ATOMIC_RELAXED, __HIP_MEMORY_SCOPE_AGENT) < target)
        __builtin_amdgcn_s_sleep(1);
    }
  }
  __syncthreads();
  __builtin_amdgcn_fence(__ATOMIC_ACQUIRE, "agent");
  epoch++;
}

// ---------------- prep kernels ----------------
__global__ void __launch_bounds__(256) k_init(const float* b_vm, float* pe, u16* emb, float* loss, unsigned* bar){
  int tid=threadIdx.x;
  if (tid==0) loss[0]=0.f;
  for(int idx=tid; idx<2048; idx+=256) bar[idx]=0u;
  for(int idx=tid; idx<16384; idx+=256) emb[idx] = f2bf(b_vm[idx&1023]);
  for(int idx=tid; idx<25600; idx+=256){
    int p_=idx>>10, d_=idx&1023; int m=d_>>1;
    float div = expf(-(float)(2*m) * (9.210340372f/1024.f));
    float a = (float)p_ * div;
    pe[idx] = (d_&1)? cosf(a) : sinf(a);
  }
}

__global__ void __launch_bounds__(256) k_f2bf(const float* s, u16* d, int n){
  int idx=(blockIdx.x*256+threadIdx.x)*8;
  if (idx < n){
    #pragma unroll
    for(int j=0;j<8;j++) d[idx+j]=f2bf(s[idx+j]);
  }
}

// dst[j*ldd+rr] = (rr<R) ? src[rr*C+j] : 0
__global__ void __launch_bounds__(256) k_tr(const float* src, int R, int C, u16* dst, int ldd){
  __shared__ float TL[32][33];
  int cb=(C+31)/32;
  int bj=blockIdx.x%cb, br=blockIdx.x/cb;
  int j0=bj*32, r0=br*32;
  int lj=threadIdx.x&31, lr=threadIdx.x>>5;
  #pragma unroll
  for(int p=0;p<4;p++){ int rr=r0+lr+p*8, jj=j0+lj;
    TL[lr+p*8][lj] = (rr<R && jj<C)? src[(size_t)rr*C+jj] : 0.f; }
  __syncthreads();
  #pragma unroll
  for(int p=0;p<4;p++){ int jj=j0+lr+p*8, rr=r0+lj;
    if (jj<C && rr<ldd) dst[(size_t)jj*ldd+rr] = f2bf(TL[lj][lr+p*8]); }
}

// generic 16x16-tile GEMM for prep: A f32 [lda], Bw bf16 row-major [Kpad]
DEV float gemm_tile16g(const u16* SLu, int lds_stride, const u16* W, int Kext, int wstride, int colbase, float* FB){
  int tid=threadIdx.x, wv=tid>>6, ln=tid&63;
  int r=ln&15, kq=ln>>4;
  int kpw=Kext>>2, k0=wv*kpw;
  const u16* ap = SLu + r*lds_stride + k0 + kq*8;
  const u16* bp = W + (size_t)(colbase+r)*wstride + k0 + kq*8;
  f32x4 acc={0.f,0.f,0.f,0.f};
  for(int k=0;k<kpw;k+=32)
    acc = __builtin_amdgcn_mfma_f32_16x16x32_bf16(*(const s16x8*)(ap+k), *(const s16x8*)(bp+k), acc, 0,0,0);
  #pragma unroll
  for(int j=0;j<4;j++) FB[wv*256 + (kq*4+j)*16 + r] = acc[j];
  __syncthreads();
  int row=tid>>4, col=tid&15;
  float s=(FB[row*16+col]+FB[256+row*16+col])+(FB[512+row*16+col]+FB[768+row*16+col]);
  __syncthreads();
  return s;
}

__global__ void __launch_bounds__(256) k_gemm_pre(const float* A, int lda, int Kreal, int Kpad,
                                                  const u16* Bw, u16* out, int ldo, int Ntiles){
  __shared__ u16 SL[16*1416];
  __shared__ float FB[1024];
  int bx=blockIdx.x; int mt=bx/Ntiles, nt=bx%Ntiles;
  int tid=threadIdx.x;
  int cpt = Kpad>>4;
  { int row=tid>>4, c0=(tid&15)*cpt;
    const float* s=A + (size_t)(mt*16+row)*lda;
    u16* d=SL + row*(Kpad+8);
    for(int c=0;c<cpt;c++){ int k=c0+c; d[k] = (k<Kreal)? f2bf(s[k]) : (u16)0; }
    __syncthreads();
  }
  float v = gemm_tile16g(SL, Kpad+8, Bw, Kpad, Kpad, nt*16, FB);
  int row=tid>>4, col=tid&15;
  out[(size_t)(mt*16+row)*ldo + nt*16+col] = f2bf(v);
}

__global__ void __launch_bounds__(256) k_bvec(const float* caWk, const float* ca_bk, const float* b_af,
                                              const float* caWv, const float* ca_bv,
                                              const float* Wvm, const float* b_vr, const float* b_vm,
                                              float* bkp, float* bvp, float* bcomb){
  __shared__ float VB[1408];
  int seg=blockIdx.x>>2, ch=blockIdx.x&3; int o=ch*256+threadIdx.x;
  const float* vec = (seg==2)? b_vr : b_af; int K = (seg==2)?1404:1024;
  for(int k=threadIdx.x;k<K;k+=256) VB[k]=vec[k];
  __syncthreads();
  const float* Arow = (seg==0)? caWk+(size_t)o*1024 : (seg==1)? caWv+(size_t)o*1024 : Wvm+(size_t)o*1404;
  float s=0.f;
  for(int k=0;k<K;k++) s += Arow[k]*VB[k];
  if(seg==0) bkp[o]=s+ca_bk[o]; else if(seg==1) bvp[o]=s+ca_bv[o]; else bcomb[o]=s+b_vm[o];
}

// mem_k (oct layout) / mem_v (normal) = audio @ Wk'/Wv'^T + bias
__global__ void __launch_bounds__(256) k_mem(const float* audio, const u16* wkp, const u16* wvp,
                                             const float* bkp, const float* bvp, u16* mt8, u16* memv){
  __shared__ u16 SL[16*776];
  int bx=blockIdx.x; int mt=bx>>3, cbk=bx&7;
  int tid=threadIdx.x, wv=tid>>6, ln=tid&63;
  { int row=tid>>4, c0=(tid&15)*48;
    const float* s = audio + (size_t)(mt*16+row)*768 + c0;
    u16* d = SL + row*776 + c0;
    #pragma unroll
    for(int c=0;c<48;c+=8){ s16x8 o;
      #pragma unroll
      for(int j=0;j<8;j++) o[j]=(short)f2bf(s[c+j]);
      *(s16x8*)(d+c)=o; }
    __syncthreads();
  }
  int r=ln&15, kq=ln>>4;
  const u16* ap = SL + r*776 + kq*8;
  for(int rep=0;rep<2;rep++){
    int colb = cbk*128 + wv*32 + rep*16;
    for(int mat=0;mat<2;mat++){
      const u16* W = mat? wvp : wkp;
      const u16* bp = W + (size_t)(colb+r)*768 + kq*8;
      f32x4 acc={0.f,0.f,0.f,0.f};
      for(int k=0;k<768;k+=32)
        acc = __builtin_amdgcn_mfma_f32_16x16x32_bf16(*(const s16x8*)(ap+k), *(const s16x8*)(bp+k), acc, 0,0,0);
      const float* bias = mat? bvp:bkp;
      int o = colb + r;
      float bo = bias[o];
      #pragma unroll
      for(int j=0;j<4;j++){ int row_=kq*4+j;
        int g = mt*16+row_;
        float val = acc[j] + bo;
        if (mat){
          memv[(size_t)g*1024 + o] = f2bf(val);
        } else {
          int bb=g/1200, ss=g-bb*1200;
          mt8[(((size_t)(bb*4 + (o>>8))*32 + ((o&255)>>3))*1200 + ss)*8 + (o&7)] = f2bf(val);
        }
      }
    }
  }
}

// ---------------- main sequential loop (plain launch, 256 co-resident blocks) ----------------
struct LoopArgs {
  const float *sa_bq,*sa_bk,*sa_bv,*sa_bo,*ca_bq,*ca_bo,*b_ff1,*b_ff2;
  const float *g1,*be1,*g2,*be2,*g3,*be3;
  char* ws;
};

__global__ void __launch_bounds__(256) k_loop(LoopArgs A){
  __shared__ u16 WL[3*16*1024];      // 96 KB: swizzled resident weight slots
  __shared__ u16 SL[16*1032];        // 33 KB staging
  __shared__ float FB[1024];         // 4 KB
  __shared__ float PL[608];
  __shared__ float RB[640];
  __shared__ float STm[16], STr[16]; // total ~137 KB LDS -> 1 wg/CU

  char* ws = A.ws;
  const u16* wq   =(const u16*)(ws+OFF_WQ);
  const u16* wk   =(const u16*)(ws+OFF_WK);
  const u16* wv_  =(const u16*)(ws+OFF_WV);
  const u16* wo   =(const u16*)(ws+OFF_WO);
  const u16* cawq =(const u16*)(ws+OFF_CAWQ);
  const u16* cawo =(const u16*)(ws+OFF_CAWO);
  const u16* ff1  =(const u16*)(ws+OFF_FF1);
  const u16* ff2  =(const u16*)(ws+OFF_FF2);
  const u16* mb   =(const u16*)(ws+OFF_MB);
  const float* pe =(const float*)(ws+OFF_PE);
  const float* bcomb=(const float*)(ws+OFF_BCOMB);
  const u16* mt8  =(const u16*)(ws+OFF_MEMK);
  const u16* memv =(const u16*)(ws+OFF_MEMV);
  u16* kt8=(u16*)(ws+OFF_KC);
  u16* vt8=(u16*)(ws+OFF_VC);
  u16* u3s=(u16*)(ws+OFF_U3S);
  float* st3=(float*)(ws+OFF_ST3);
  u16* emb=(u16*)(ws+OFF_EMB);
  u16* qb =(u16*)(ws+OFF_QB);
  u16* sab=(u16*)(ws+OFF_SA);
  u16* u1 =(u16*)(ws+OFF_U1);
  float* st1=(float*)(ws+OFF_ST1);
  u16* q2b=(u16*)(ws+OFF_Q2);
  u16* cab=(u16*)(ws+OFF_CA);
  u16* u2 =(u16*)(ws+OFF_U2);
  float* st2=(float*)(ws+OFF_ST2);
  u16* hh =(u16*)(ws+OFF_HH);
  char* barb=(char*)(ws+OFF_BAR);

  unsigned epoch = 0;
  int wg = blockIdx.x, tid = threadIdx.x;
  int row = tid>>4, lo = tid&15;
  int grp = wg>>6, ct = (wg&63)<<4;

  // ---- one-time: preload this wg's weight tiles into LDS (swizzled) ----
  {
    u16* s0d = WL;          u16* s1d = WL+16384;  u16* s2d = WL+32768;
    if (grp==0){
      copy_slot(wq  +(size_t)ct*1024,1024,s0d);
      copy_slot(cawq+(size_t)ct*1024,1024,s1d);
      copy_slot(ff1 +(size_t)ct*1024,1024,s2d);
    } else if (grp==1){
      copy_slot(wk  +(size_t)ct*1024,1024,s0d);
      copy_slot(cawo+(size_t)ct*1024,1024,s1d);
      copy_slot(ff1 +((size_t)(1024+ct))*1024,1024,s2d);
    } else if (grp==2){
      copy_slot(wv_ +(size_t)ct*1024,1024,s0d);
      copy_slot(ff2 +(size_t)ct*2048,2048,s1d);
      copy_slot(ff2 +(size_t)ct*2048+1024,2048,s2d);
    } else {
      copy_slot(wo  +(size_t)ct*1024,1024,s0d);
      copy_slot(mb  +(size_t)ct*1024,1024,s1d);
    }
    __syncthreads();
  }
  const u16* SLOT0 = WL;
  const u16* SLOT1 = WL+16384;
  const u16* SLOT2 = WL+32768;

  #pragma unroll 1
  for (int i=0;i<600;i++){
    int ip = i%25;

    // ---- phase A: x = emb + pe ; q/k/v projections (192 wgs) ----
    if (wg < 192){
      { int c0 = lo<<6;
        const u16* s = emb + row*1024 + c0;
        const float* pp = pe + ip*1024 + c0;
        u16* d = SL + row*1032 + c0;
        #pragma unroll
        for(int c=0;c<64;c+=8){ s16x8 e = *(const s16x8*)(s+c); s16x8 o;
          #pragma unroll
          for(int j=0;j<8;j++) o[j] = (short)f2bf(bf2f((u16)e[j]) + pp[c+j]);
          *(s16x8*)(d+c) = o; }
        __syncthreads();
      }
      const float* bias = (grp==0)? A.sa_bq : (grp==1)? A.sa_bk : A.sa_bv;
      float v = gemm_w(SL,1032,SLOT0,FB);
      int o = ct + lo;
      float val = v + bias[o];
      if (grp==0){
        qb[row*1024 + o] = f2bf(val);
      } else {
        u16* kv = (grp==1)? kt8 : vt8;
        kv[(((size_t)(row*4 + (o>>8))*32 + ((o&255)>>3))*600 + i)*8 + (o&7)] = f2bf(val);
      }
    }
    gbar(barb, epoch);

    // ---- phase B: full self-attn for one (b,h) (64 wgs) ----
    if (wg < 64){
      int b=wg>>2, h=wg&3, cnt=i+1;
      RB[tid] = bf2f(qb[b*1024 + h*256 + tid]);
      __syncthreads();
      const u16* KT = kt8 + (size_t)(b*4+h)*32*600*8;
      float sl = 1.0f/(float)(4<<(2*h));
      float mx=-1e30f;
      for(int t=tid; t<cnt; t+=256){
        float s=0.f;
        #pragma unroll 8
        for(int oc=0; oc<32; oc++){
          s16x8 k8 = *(const s16x8*)(KT + ((size_t)oc*600 + t)*8);
          #pragma unroll
          for(int j=0;j<8;j++) s += RB[oc*8+j]*bf2f((u16)k8[j]);
        }
        s = s*0.0625f - sl*(float)((i-t)/25);
        PL[t]=s; mx=fmaxf(mx,s);
      }
      mx = brmax(mx,RB);
      float ls=0.f;
      for(int t=tid;t<cnt;t+=256){ float e=__expf(PL[t]-mx); PL[t]=e; ls+=e; }
      float l = brsum(ls,RB);
      float rl = 1.0f/l;
      int d_oct = tid>>3, t_ln = tid&7;
      const u16* VT = vt8 + ((size_t)(b*4+h)*32 + d_oct)*600*8;
      float acc[8]={0.f,0.f,0.f,0.f,0.f,0.f,0.f,0.f};
      for(int t=t_ln; t<cnt; t+=8){
        s16x8 v8 = *(const s16x8*)(VT + (size_t)t*8);
        float p = PL[t];
        #pragma unroll
        for(int j=0;j<8;j++) acc[j] += p*bf2f((u16)v8[j]);
      }
      #pragma unroll
      for(int j=0;j<8;j++){
        acc[j] += __shfl_xor(acc[j],1);
        acc[j] += __shfl_xor(acc[j],2);
        acc[j] += __shfl_xor(acc[j],4);
      }
      if (t_ln==0){
        s16x8 o8;
        #pragma unroll
        for(int j=0;j<8;j++) o8[j]=(short)f2bf(acc[j]*rl);
        *(s16x8*)(sab + b*1024 + h*256 + d_oct*8) = o8;
      }
      __syncthreads();
    }
    gbar(barb, epoch);

    // ---- phase C: u1 = x + sa@Wo^T + bo (wgs 192..255) ----
    if (wg>=192){
      stage16(sab, SL);
      float v = gemm_w(SL,1032,SLOT0,FB);
      int o = ct+lo;
      float x = bf2f(emb[row*1024+o]) + pe[ip*1024+o];
      u1[row*1024+o] = f2bf(x + v + A.sa_bo[o]);
    }
    gbar(barb, epoch);

    // ---- phase D: q2 = LN1(u1)@caWq^T + bq (wgs 0..63) ----
    if (wg<64){
      stage_ln16(u1, A.g1, A.be1, SL, RB, STm, STr);
      float v = gemm_w(SL,1032,SLOT1,FB);
      int o=ct+lo;
      q2b[row*1024+o] = f2bf(v + A.ca_bq[o]);
      if (wg==0 && tid<16){ st1[tid*2]=STm[tid]; st1[tid*2+1]=STr[tid]; }
    }
    gbar(barb, epoch);

    // ---- phase E: windowed cross-attn -> ca (wgs 0..63) ----
    if (wg<64){
      int b=wg>>2, h=wg&3;
      RB[tid] = bf2f(q2b[b*1024 + h*256 + tid]);
      __syncthreads();
      int s0 = 2*i-6; if(s0<0)s0=0;
      int s1 = 2*i+2; if(s1>1200)s1=1200;
      int ns = s1-s0;
      int si=tid>>5, dl=tid&31;
      float p=0.f;
      if (si<ns){
        const u16* MT = mt8 + (((size_t)(b*4+h)*32 + dl)*1200 + (s0+si))*8;
        s16x8 m8 = *(const s16x8*)MT;
        #pragma unroll
        for(int j=0;j<8;j++) p += RB[dl*8+j]*bf2f((u16)m8[j]);
      }
      #pragma unroll
      for(int o2=16;o2>0;o2>>=1) p += __shfl_xor(p,o2);
      if (dl==0 && si<ns) RB[512+si] = p*0.0625f;
      __syncthreads();
      float mx=-1e30f;
      for(int q=0;q<ns;q++) mx=fmaxf(mx,RB[512+q]);
      float l=0.f, acc=0.f;
      for(int q=0;q<ns;q++){
        float e=__expf(RB[512+q]-mx); l+=e;
        acc += e*bf2f(memv[(size_t)(b*1200+s0+q)*1024 + h*256 + tid]);
      }
      cab[b*1024+h*256+tid] = f2bf(acc/l);
      __syncthreads();
    }
    gbar(barb, epoch);

    // ---- phase F: u2 = x1 + ca@caWo^T + bo2 (wgs 64..127) ----
    if (wg>=64 && wg<128){
      stage16(cab, SL);
      float v = gemm_w(SL,1032,SLOT1,FB);
      int o=ct+lo;
      float m1=st1[row*2], r1=st1[row*2+1];
      float x1 = (bf2f(u1[row*1024+o])-m1)*r1*A.g1[o] + A.be1[o];
      u2[row*1024+o] = f2bf(x1 + v + A.ca_bo[o]);
    }
    gbar(barb, epoch);

    // ---- phase G: hh = relu(LN2(u2)@FF1^T + b1) (wgs 0..127) ----
    if (wg<128){
      stage_ln16(u2, A.g2, A.be2, SL, RB, STm, STr);
      float v = gemm_w(SL,1032,SLOT2,FB);
      int o=(wg<<4)+lo;
      hh[row*2048+o] = f2bf(fmaxf(v + A.b_ff1[o], 0.f));
      if (wg==0 && tid<16){ st2[tid*2]=STm[tid]; st2[tid*2+1]=STr[tid]; }
    }
    gbar(barb, epoch);

    // ---- phase H: u3 = x2 + hh@FF2^T + b2 (wgs 128..191; K=2048 via two slots) ----
    if (wg>=128 && wg<192){
      stage16_src(hh, 2048, 0, SL);
      float v = gemm_w(SL,1032,SLOT1,FB);
      stage16_src(hh, 2048, 1024, SL);
      v += gemm_w(SL,1032,SLOT2,FB);
      int o=ct+lo;
      float m2=st2[row*2], r2=st2[row*2+1];
      float x2 = (bf2f(u2[row*1024+o])-m2)*r2*A.g2[o] + A.be2[o];
      u3s[(i*16+row)*1024+o] = f2bf(x2 + v + A.b_ff2[o]);
    }
    gbar(barb, epoch);

    // ---- phase I: emb = LN3(u3)@M^T + bcomb (wgs 192..255) ----
    if (wg>=192){
      stage_ln16(u3s + i*16384, A.g3, A.be3, SL, RB, STm, STr);
      float v = gemm_w(SL,1032,SLOT1,FB);
      int o=ct+lo;
      emb[row*1024+o] = f2bf(v + bcomb[o]);
      if (wg==192 && tid<16){ st3[i*32+tid*2]=STm[tid]; st3[i*32+tid*2+1]=STr[tid]; }
    }
    gbar(barb, epoch);
  }
}

// ---------------- deferred loss ----------------
__global__ void __launch_bounds__(256) k_loss(const u16* u3s, const float* st3, const u16* wvr,
                                              const float* bvr, const float* g3, const float* be3,
                                              const float* vert, float* loss){
  __shared__ u16 SL[16*1032];
  __shared__ float R[64];
  int bx=blockIdx.x; int ib=bx/11, cb=bx%11;
  int tid=threadIdx.x, wvv=tid>>6, ln=tid&63;
  int r=ln&15, kq=ln>>4;
  float lsum=0.f;
  for(int ii=0;ii<8;ii++){
    int i=ib*8+ii;
    { int row=tid>>4, c0=(tid&15)<<6;
      float m=st3[i*32+row*2], rs=st3[i*32+row*2+1];
      const u16* s=u3s + (size_t)(i*16+row)*1024 + c0;
      u16* d=SL + row*1032 + c0;
      #pragma unroll
      for(int c=0;c<64;c+=8){ s16x8 v=*(const s16x8*)(s+c); s16x8 o;
        #pragma unroll
        for(int j=0;j<8;j++){ int cc=c0+c+j; o[j]=(short)f2bf((bf2f((u16)v[j])-m)*rs*g3[cc]+be3[cc]); }
        *(s16x8*)(d+c)=o; }
      __syncthreads();
    }
    const u16* ap = SL + r*1032 + kq*8;
    for(int rep=0;rep<2;rep++){
      int colb = cb*128 + wvv*32 + rep*16;
      int o_r = colb + r; bool ok = o_r < 1404;
      const u16* bp = wvr + (size_t)(ok? o_r:0)*1024 + kq*8;
      f32x4 acc={0.f,0.f,0.f,0.f};
      for(int k=0;k<1024;k+=32)
        acc = __builtin_amdgcn_mfma_f32_16x16x32_bf16(*(const s16x8*)(ap+k), *(const s16x8*)(bp+k), acc, 0,0,0);
      if (ok){
        float bo = bvr[o_r];
        #pragma unroll
        for(int j=0;j<4;j++){
          int b_=kq*4+j;
          float ov = acc[j] + bo;
          float vt = vert[(size_t)(b_*600 + i)*1404 + o_r];
          float dd = ov - vt; lsum += dd*dd;
        }
      }
    }
    __syncthreads();
  }
  #pragma unroll
  for(int o=32;o>0;o>>=1) lsum += __shfl_down(lsum,o);
  if (ln==0) R[wvv]=lsum;
  __syncthreads();
  if (tid==0) atomicAdd(loss, (R[0]+R[1])+(R[2]+R[3]));
}

__global__ void k_fin(const float* loss, float* dout){
  if (threadIdx.x==0) dout[0] = loss[0] * (1.f/13478400.f);   // / (16*600*1404)
}

// ---------------- host ----------------
extern "C" void kernel_launch(void* const* d_in, const int* in_sizes, int n_in,
                              void* d_out, int out_size, void* d_ws, size_t ws_size,
                              hipStream_t stream){
  char* ws = (char*)d_ws;
  if (ws_size < WS_NEED){ hipMemsetAsync(d_out, 0, 4, stream); return; }

  const float* audio=(const float*)d_in[0];
  const float* vert =(const float*)d_in[1];
  const float* W_af =(const float*)d_in[2];
  const float* b_af =(const float*)d_in[3];
  const float* saWq =(const float*)d_in[4];  const float* sa_bq=(const float*)d_in[5];
  const float* saWk =(const float*)d_in[6];  const float* sa_bk=(const float*)d_in[7];
  const float* saWv =(const float*)d_in[8];  const float* sa_bv=(const float*)d_in[9];
  const float* saWo =(const float*)d_in[10]; const float* sa_bo=(const float*)d_in[11];
  const float* caWq =(const float*)d_in[12]; const float* ca_bq=(const float*)d_in[13];
  const float* caWk =(const float*)d_in[14]; const float* ca_bk=(const float*)d_in[15];
  const float* caWv =(const float*)d_in[16]; const float* ca_bv=(const float*)d_in[17];
  const float* caWo =(const float*)d_in[18]; const float* ca_bo=(const float*)d_in[19];
  const float* g1=(const float*)d_in[20]; const float* be1=(const float*)d_in[21];
  const float* g2=(const float*)d_in[22]; const float* be2=(const float*)d_in[23];
  const float* g3=(const float*)d_in[24]; const float* be3=(const float*)d_in[25];
  const float* Wff1=(const float*)d_in[26]; const float* b_ff1=(const float*)d_in[27];
  const float* Wff2=(const float*)d_in[28]; const float* b_ff2=(const float*)d_in[29];
  const float* Wvm=(const float*)d_in[30];  const float* b_vm=(const float*)d_in[31];
  const float* Wvr=(const float*)d_in[32];  const float* b_vr=(const float*)d_in[33];

  k_init<<<1,256,0,stream>>>(b_vm, (float*)(ws+OFF_PE), (u16*)(ws+OFF_EMB), (float*)(ws+OFF_LOSS), (unsigned*)(ws+OFF_BAR));

  k_f2bf<<<512,256,0,stream>>>(saWq,(u16*)(ws+OFF_WQ),1048576);
  k_f2bf<<<512,256,0,stream>>>(saWk,(u16*)(ws+OFF_WK),1048576);
  k_f2bf<<<512,256,0,stream>>>(saWv,(u16*)(ws+OFF_WV),1048576);
  k_f2bf<<<512,256,0,stream>>>(saWo,(u16*)(ws+OFF_WO),1048576);
  k_f2bf<<<512,256,0,stream>>>(caWq,(u16*)(ws+OFF_CAWQ),1048576);
  k_f2bf<<<512,256,0,stream>>>(caWo,(u16*)(ws+OFF_CAWO),1048576);
  k_f2bf<<<1024,256,0,stream>>>(Wff1,(u16*)(ws+OFF_FF1),2097152);
  k_f2bf<<<1024,256,0,stream>>>(Wff2,(u16*)(ws+OFF_FF2),2097152);
  k_f2bf<<<702,256,0,stream>>>(Wvr,(u16*)(ws+OFF_WVR),1437696);

  k_tr<<<24*32,256,0,stream>>>(W_af, 1024, 768, (u16*)(ws+OFF_WAFT), 1024);
  k_tr<<<32*44,256,0,stream>>>(Wvr, 1404, 1024, (u16*)(ws+OFF_WVRT), 1408);

  k_gemm_pre<<<64*48,256,0,stream>>>(caWk, 1024, 1024, 1024, (const u16*)(ws+OFF_WAFT), (u16*)(ws+OFF_WKP), 768, 48);
  k_gemm_pre<<<64*48,256,0,stream>>>(caWv, 1024, 1024, 1024, (const u16*)(ws+OFF_WAFT), (u16*)(ws+OFF_WVP), 768, 48);
  k_gemm_pre<<<64*64,256,0,stream>>>(Wvm, 1404, 1404, 1408, (const u16*)(ws+OFF_WVRT), (u16*)(ws+OFF_MB), 1024, 64);

  k_bvec<<<12,256,0,stream>>>(caWk, ca_bk, b_af, caWv, ca_bv, Wvm, b_vr, b_vm,
                              (float*)(ws+OFF_BKP),(float*)(ws+OFF_BVP),(float*)(ws+OFF_BCOMB));

  k_mem<<<9600,256,0,stream>>>(audio, (const u16*)(ws+OFF_WKP),(const u16*)(ws+OFF_WVP),
                               (const float*)(ws+OFF_BKP),(const float*)(ws+OFF_BVP),
                               (u16*)(ws+OFF_MEMK),(u16*)(ws+OFF_MEMV));

  LoopArgs la{ sa_bq, sa_bk, sa_bv, sa_bo, ca_bq, ca_bo, b_ff1, b_ff2,
               g1, be1, g2, be2, g3, be3, ws };
  k_loop<<<256,256,0,stream>>>(la);

  k_loss<<<825,256,0,stream>>>((const u16*)(ws+OFF_U3S),(const float*)(ws+OFF_ST3),
                               (const u16*)(ws+OFF_WVR), b_vr, g3, be3, vert, (float*)(ws+OFF_LOSS));
  k_fin<<<1,64,0,stream>>>((const float*)(ws+OFF_LOSS), (float*)d_out);
}

// Round 5
// 45939.764 us; speedup vs baseline: 4.4085x; 2.9775x over previous
//
#include <hip/hip_runtime.h>

typedef unsigned short u16;
typedef short s16x8 __attribute__((ext_vector_type(8)));
typedef float f32x4 __attribute__((ext_vector_type(4)));
typedef float f32x2 __attribute__((ext_vector_type(2)));

#define DEV static __device__ __forceinline__

DEV float bf2f(u16 h){ union{unsigned u;float f;} v; v.u=((unsigned)h)<<16; return v.f; }
DEV u16 f2bf(float f){ union{float f;unsigned u;} v; v.f=f; unsigned u=v.u; return (u16)((u + 0x7fffu + ((u>>16)&1u))>>16); }

// ---------------- device-coherent IO (sc0 sc1: bypass L1/L2 -> L3 coherence point; no fences needed) ----------------
DEV void st2_dc(u16* p, u16 v){
  unsigned vv = v;
  asm volatile("global_store_short %0, %1, off sc0 sc1" :: "v"(p), "v"(vv) : "memory");
}
DEV void st16_dc(void* p, s16x8 v){
  asm volatile("global_store_dwordx4 %0, %1, off sc0 sc1" :: "v"(p), "v"(v) : "memory");
}
DEV void stf_dc(float* p, float v){
  asm volatile("global_store_dword %0, %1, off sc0 sc1" :: "v"(p), "v"(v) : "memory");
}
DEV u16 ld2_dc(const u16* p){
  unsigned r;
  asm volatile("global_load_ushort %0, %1, off sc0 sc1\n\ts_waitcnt vmcnt(0)" : "=&v"(r) : "v"(p) : "memory");
  return (u16)r;
}
DEV f32x2 ldf2_dc(const float* p){
  f32x2 r;
  asm volatile("global_load_dwordx2 %0, %1, off sc0 sc1\n\ts_waitcnt vmcnt(0)" : "=&v"(r) : "v"(p) : "memory");
  return r;
}
// single 16B coherent load, NO wait (issue-only); single-instruction asm cannot alias-corrupt
#define LD16O(dst, p, OFFSTR) \
  asm volatile("global_load_dwordx4 %0, %1, off offset:" OFFSTR " sc0 sc1" : "=&v"(dst) : "v"(p) : "memory")
DEV void ld16_nw(const u16* p, s16x8* d){
  asm volatile("global_load_dwordx4 %0, %1, off sc0 sc1" : "=&v"(*d) : "v"(p) : "memory");
}
DEV void vmwait0(){ asm volatile("s_waitcnt vmcnt(0)" ::: "memory"); }
// 8 x 16B in flight (128B), no wait
DEV void ld8_nw(const u16* p, s16x8* o){
  LD16O(o[0],p,"0");  LD16O(o[1],p,"16"); LD16O(o[2],p,"32"); LD16O(o[3],p,"48");
  LD16O(o[4],p,"64"); LD16O(o[5],p,"80"); LD16O(o[6],p,"96"); LD16O(o[7],p,"112");
}
DEV void ld128_dc(const u16* p, s16x8* o){ ld8_nw(p,o); vmwait0(); }

// ---------------- workspace layout (bytes) ----------------
constexpr size_t SZ_DD = (size_t)1024*1024*2;
constexpr size_t OFF_WQ=0;
constexpr size_t OFF_WK=OFF_WQ+SZ_DD;
constexpr size_t OFF_WV=OFF_WK+SZ_DD;
constexpr size_t OFF_WO=OFF_WV+SZ_DD;
constexpr size_t OFF_CAWQ=OFF_WO+SZ_DD;
constexpr size_t OFF_CAWO=OFF_CAWQ+SZ_DD;
constexpr size_t OFF_FF1=OFF_CAWO+SZ_DD;                    // 2048x1024 bf16
constexpr size_t OFF_FF2=OFF_FF1+(size_t)2048*1024*2;       // 1024 rows x 2048 K bf16
constexpr size_t OFF_MB =OFF_FF2+(size_t)2048*1024*2;       // 1024x1024 bf16 (Wvm@Wvr)
constexpr size_t OFF_WVR=OFF_MB+SZ_DD;                      // 1404x1024 bf16
constexpr size_t OFF_WKP=OFF_WVR+(size_t)1404*1024*2;       // 1024x768 bf16
constexpr size_t OFF_WVP=OFF_WKP+(size_t)1024*768*2;
constexpr size_t OFF_WAFT=OFF_WVP+(size_t)1024*768*2;       // 768x1024 bf16 (W_af^T)
constexpr size_t OFF_WVRT=OFF_WAFT+(size_t)768*1024*2;      // 1024x1408 bf16 (Wvr^T padded)
constexpr size_t OFF_PE  =OFF_WVRT+(size_t)1024*1408*2;     // 25x1024 f32
constexpr size_t OFF_BKP =OFF_PE+25*1024*4;                 // 1024 f32
constexpr size_t OFF_BVP =OFF_BKP+4096;
constexpr size_t OFF_BCOMB=OFF_BVP+4096;
constexpr size_t OFF_MEMK=OFF_BCOMB+4096;                   // oct layout [16][4][32][1200][8] bf16
constexpr size_t OFF_MEMV=OFF_MEMK+(size_t)16*1200*1024*2;  // [b*1200+s][1024]
constexpr size_t OFF_KC  =OFF_MEMV+(size_t)16*1200*1024*2;  // [(t*16+b)][1024] bf16
constexpr size_t OFF_VC  =OFF_KC+(size_t)600*16*1024*2;
constexpr size_t OFF_U3S =OFF_VC+(size_t)600*16*1024*2;     // 600x16x1024 bf16
constexpr size_t OFF_ST3 =OFF_U3S+(size_t)600*16*1024*2;    // 600x16x2 f32
constexpr size_t OFF_EMB =OFF_ST3+600*32*4;                 // 16x1024 bf16
constexpr size_t OFF_QB  =OFF_EMB+32768;
constexpr size_t OFF_SC  =OFF_QB+32768;                     // (reserved)
constexpr size_t OFF_SA  =OFF_SC+(size_t)16*4*608*4;
constexpr size_t OFF_U1  =OFF_SA+32768;
constexpr size_t OFF_ST1 =OFF_U1+32768;                     // 32 f32
constexpr size_t OFF_Q2  =OFF_ST1+256;
constexpr size_t OFF_CA  =OFF_Q2+32768;
constexpr size_t OFF_U2  =OFF_CA+32768;
constexpr size_t OFF_ST2 =OFF_U2+32768;
constexpr size_t OFF_HH  =OFF_ST2+256;                      // 16x2048 bf16
constexpr size_t OFF_LOSS=OFF_HH+65536;
constexpr size_t OFF_BAR =OFF_LOSS+256;                     // 18 x 256B barrier lines
constexpr size_t WS_NEED =OFF_BAR+8192;

// ---------------- shared helpers ----------------
DEV float brmax(float v, float* R){
  #pragma unroll
  for(int o=32;o>0;o>>=1) v = fmaxf(v, __shfl_down(v,o));
  if ((threadIdx.x&63)==0) R[576+(threadIdx.x>>6)] = v;
  __syncthreads();
  v = fmaxf(fmaxf(R[576],R[577]), fmaxf(R[578],R[579]));
  __syncthreads();
  return v;
}
DEV float brsum(float v, float* R){
  #pragma unroll
  for(int o=32;o>0;o>>=1) v += __shfl_down(v,o);
  if ((threadIdx.x&63)==0) R[580+(threadIdx.x>>6)] = v;
  __syncthreads();
  v = (R[580]+R[581])+(R[582]+R[583]);
  __syncthreads();
  return v;
}

// GEMM 16x16 tile: A from SL (stride lds_stride), B from swizzled LDS weight slot
DEV float gemm_w(const u16* SLu, int lds_stride, const u16* slot, float* FB){
  int tid=threadIdx.x, wv=tid>>6, ln=tid&63;
  int r=ln&15, kq=ln>>4;
  int k0=wv*256 + kq*8;
  const u16* ap = SLu + r*lds_stride + k0;
  int sw=(r&7)<<3;
  const u16* bp = slot + r*1024;
  f32x4 acc={0.f,0.f,0.f,0.f};
  #pragma unroll
  for(int k=0;k<1024;k+=128)
    acc = __builtin_amdgcn_mfma_f32_16x16x32_bf16(*(const s16x8*)(ap+(k>>2)),
                                                  *(const s16x8*)(bp + (((k0+(k>>2)))^sw)), acc, 0,0,0);
  #pragma unroll
  for(int j=0;j<4;j++) FB[wv*256 + (kq*4+j)*16 + r] = acc[j];
  __syncthreads();
  int row=tid>>4, col=tid&15;
  float s=(FB[row*16+col]+FB[256+row*16+col])+(FB[512+row*16+col]+FB[768+row*16+col]);
  __syncthreads();
  return s;
}

// copy one 16x1024 bf16 weight tile (global, row stride rstride) into swizzled LDS slot (cached reads: prep-written)
DEV void copy_slot(const u16* src, int rstride, u16* dst){
  int row=threadIdx.x>>4, k0=(threadIdx.x&15)<<6;
  int sw=(row&7)<<3;
  const u16* s = src + (size_t)row*rstride + k0;
  u16* d = dst + row*1024;
  #pragma unroll
  for(int c=0;c<64;c+=8)
    *(s16x8*)(d + (((k0+c))^sw)) = *(const s16x8*)(s+c);
}

// stage 16x1024 via device-coherent loads into SL[16][1032]
DEV void stage16_dc(const u16* src, int srcstride, int c0base, u16* SL){
  int row=threadIdx.x>>4, c0=(threadIdx.x&15)<<6;
  s16x8 o[8];
  ld128_dc(src + (size_t)row*srcstride + c0base + c0, o);
  u16* d=SL+row*1032+c0;
  #pragma unroll
  for(int c=0;c<8;c++) *(s16x8*)(d+c*8) = o[c];
  __syncthreads();
}

// stage u (16x1024, device-coherent) applying LayerNorm(g,be); stats in STm/STr.
DEV void stage_ln16_dc(const u16* u, const float* g, const float* be, u16* SL, float* RB, float* STm, float* STr){
  int tid=threadIdx.x; int row=tid>>4, c0=(tid&15)<<6;
  s16x8 vr[8];
  ld128_dc(u + (size_t)row*1024 + c0, vr);
  float sum=0.f, sq=0.f;
  #pragma unroll
  for(int c=0;c<8;c++){
    #pragma unroll
    for(int j=0;j<8;j++){ float f=bf2f((u16)vr[c][j]); sum+=f; sq+=f*f; }
  }
  RB[tid]=sum; RB[256+tid]=sq;
  __syncthreads();
  if (tid<16){
    float S=0.f,Q=0.f;
    #pragma unroll
    for(int k=0;k<16;k++){ S+=RB[tid*16+k]; Q+=RB[256+tid*16+k]; }
    float m=S*(1.f/1024.f); float var=Q*(1.f/1024.f)-m*m;
    STm[tid]=m; STr[tid]=rsqrtf(var+1e-5f);
  }
  __syncthreads();
  float m=STm[row], rs=STr[row];
  u16* d = SL + row*1032 + c0;
  #pragma unroll
  for(int c=0;c<8;c++){
    s16x8 o;
    #pragma unroll
    for(int j=0;j<8;j++){ int cc=c0+c*8+j; float f=(bf2f((u16)vr[c][j])-m)*rs*g[cc]+be[cc]; o[j]=(short)f2bf(f); }
    *(s16x8*)(d + c*8) = o;
  }
  __syncthreads();
}

// grid barrier: NO fences. waitcnt drains each wave's sc0sc1 stores; tree of relaxed agent atomics.
DEV void gbar(char* barb, unsigned& epoch){
  vmwait0();
  __syncthreads();
  if (threadIdx.x == 0){
    unsigned* leaf = (unsigned*)(barb + ((blockIdx.x & 15) << 8));
    unsigned* root = (unsigned*)(barb + (16 << 8));
    unsigned* flag = (unsigned*)(barb + (17 << 8));
    unsigned target = epoch + 1u;
    bool done=false;
    unsigned prev = __hip_atomic_fetch_add(leaf, 1u, __ATOMIC_RELAXED, __HIP_MEMORY_SCOPE_AGENT);
    if (prev == epoch*16u + 15u){
      unsigned p2 = __hip_atomic_fetch_add(root, 1u, __ATOMIC_RELAXED, __HIP_MEMORY_SCOPE_AGENT);
      if (p2 == epoch*16u + 15u){
        __hip_atomic_store(flag, target, __ATOMIC_RELAXED, __HIP_MEMORY_SCOPE_AGENT);
        done=true;
      }
    }
    if (!done){
      while (__hip_atomic_load(flag, __ATOMIC_RELAXED, __HIP_MEMORY_SCOPE_AGENT) < target)
        __builtin_amdgcn_s_sleep(1);
    }
  }
  __syncthreads();
  epoch++;
}

// ---------------- prep kernels ----------------
__global__ void __launch_bounds__(256) k_init(const float* b_vm, float* pe, u16* emb, float* loss, unsigned* bar){
  int tid=threadIdx.x;
  if (tid==0) loss[0]=0.f;
  for(int idx=tid; idx<2048; idx+=256) bar[idx]=0u;
  for(int idx=tid; idx<16384; idx+=256) emb[idx] = f2bf(b_vm[idx&1023]);
  for(int idx=tid; idx<25600; idx+=256){
    int p_=idx>>10, d_=idx&1023; int m=d_>>1;
    float div = expf(-(float)(2*m) * (9.210340372f/1024.f));
    float a = (float)p_ * div;
    pe[idx] = (d_&1)? cosf(a) : sinf(a);
  }
}

__global__ void __launch_bounds__(256) k_f2bf(const float* s, u16* d, int n){
  int idx=(blockIdx.x*256+threadIdx.x)*8;
  if (idx < n){
    #pragma unroll
    for(int j=0;j<8;j++) d[idx+j]=f2bf(s[idx+j]);
  }
}

__global__ void __launch_bounds__(256) k_tr(const float* src, int R, int C, u16* dst, int ldd){
  __shared__ float TL[32][33];
  int cb=(C+31)/32;
  int bj=blockIdx.x%cb, br=blockIdx.x/cb;
  int j0=bj*32, r0=br*32;
  int lj=threadIdx.x&31, lr=threadIdx.x>>5;
  #pragma unroll
  for(int p=0;p<4;p++){ int rr=r0+lr+p*8, jj=j0+lj;
    TL[lr+p*8][lj] = (rr<R && jj<C)? src[(size_t)rr*C+jj] : 0.f; }
  __syncthreads();
  #pragma unroll
  for(int p=0;p<4;p++){ int jj=j0+lr+p*8, rr=r0+lj;
    if (jj<C && rr<ldd) dst[(size_t)jj*ldd+rr] = f2bf(TL[lj][lr+p*8]); }
}

DEV float gemm_tile16g(const u16* SLu, int lds_stride, const u16* W, int Kext, int wstride, int colbase, float* FB){
  int tid=threadIdx.x, wv=tid>>6, ln=tid&63;
  int r=ln&15, kq=ln>>4;
  int kpw=Kext>>2, k0=wv*kpw;
  const u16* ap = SLu + r*lds_stride + k0 + kq*8;
  const u16* bp = W + (size_t)(colbase+r)*wstride + k0 + kq*8;
  f32x4 acc={0.f,0.f,0.f,0.f};
  for(int k=0;k<kpw;k+=32)
    acc = __builtin_amdgcn_mfma_f32_16x16x32_bf16(*(const s16x8*)(ap+k), *(const s16x8*)(bp+k), acc, 0,0,0);
  #pragma unroll
  for(int j=0;j<4;j++) FB[wv*256 + (kq*4+j)*16 + r] = acc[j];
  __syncthreads();
  int row=tid>>4, col=tid&15;
  float s=(FB[row*16+col]+FB[256+row*16+col])+(FB[512+row*16+col]+FB[768+row*16+col]);
  __syncthreads();
  return s;
}

__global__ void __launch_bounds__(256) k_gemm_pre(const float* A, int lda, int Kreal, int Kpad,
                                                  const u16* Bw, u16* out, int ldo, int Ntiles){
  __shared__ u16 SL[16*1416];
  __shared__ float FB[1024];
  int bx=blockIdx.x; int mt=bx/Ntiles, nt=bx%Ntiles;
  int tid=threadIdx.x;
  int cpt = Kpad>>4;
  { int row=tid>>4, c0=(tid&15)*cpt;
    const float* s=A + (size_t)(mt*16+row)*lda;
    u16* d=SL + row*(Kpad+8);
    for(int c=0;c<cpt;c++){ int k=c0+c; d[k] = (k<Kreal)? f2bf(s[k]) : (u16)0; }
    __syncthreads();
  }
  float v = gemm_tile16g(SL, Kpad+8, Bw, Kpad, Kpad, nt*16, FB);
  int row=tid>>4, col=tid&15;
  out[(size_t)(mt*16+row)*ldo + nt*16+col] = f2bf(v);
}

__global__ void __launch_bounds__(256) k_bvec(const float* caWk, const float* ca_bk, const float* b_af,
                                              const float* caWv, const float* ca_bv,
                                              const float* Wvm, const float* b_vr, const float* b_vm,
                                              float* bkp, float* bvp, float* bcomb){
  __shared__ float VB[1408];
  int seg=blockIdx.x>>2, ch=blockIdx.x&3; int o=ch*256+threadIdx.x;
  const float* vec = (seg==2)? b_vr : b_af; int K = (seg==2)?1404:1024;
  for(int k=threadIdx.x;k<K;k+=256) VB[k]=vec[k];
  __syncthreads();
  const float* Arow = (seg==0)? caWk+(size_t)o*1024 : (seg==1)? caWv+(size_t)o*1024 : Wvm+(size_t)o*1404;
  float s=0.f;
  for(int k=0;k<K;k++) s += Arow[k]*VB[k];
  if(seg==0) bkp[o]=s+ca_bk[o]; else if(seg==1) bvp[o]=s+ca_bv[o]; else bcomb[o]=s+b_vm[o];
}

// mem_k (oct layout) / mem_v (normal) = audio @ Wk'/Wv'^T + bias
__global__ void __launch_bounds__(256) k_mem(const float* audio, const u16* wkp, const u16* wvp,
                                             const float* bkp, const float* bvp, u16* mt8, u16* memv){
  __shared__ u16 SL[16*776];
  int bx=blockIdx.x; int mt=bx>>3, cbk=bx&7;
  int tid=threadIdx.x, wv=tid>>6, ln=tid&63;
  { int row=tid>>4, c0=(tid&15)*48;
    const float* s = audio + (size_t)(mt*16+row)*768 + c0;
    u16* d = SL + row*776 + c0;
    #pragma unroll
    for(int c=0;c<48;c+=8){ s16x8 o;
      #pragma unroll
      for(int j=0;j<8;j++) o[j]=(short)f2bf(s[c+j]);
      *(s16x8*)(d+c)=o; }
    __syncthreads();
  }
  int r=ln&15, kq=ln>>4;
  const u16* ap = SL + r*776 + kq*8;
  for(int rep=0;rep<2;rep++){
    int colb = cbk*128 + wv*32 + rep*16;
    for(int mat=0;mat<2;mat++){
      const u16* W = mat? wvp : wkp;
      const u16* bp = W + (size_t)(colb+r)*768 + kq*8;
      f32x4 acc={0.f,0.f,0.f,0.f};
      for(int k=0;k<768;k+=32)
        acc = __builtin_amdgcn_mfma_f32_16x16x32_bf16(*(const s16x8*)(ap+k), *(const s16x8*)(bp+k), acc, 0,0,0);
      const float* bias = mat? bvp:bkp;
      int o = colb + r;
      float bo = bias[o];
      #pragma unroll
      for(int j=0;j<4;j++){ int row_=kq*4+j;
        int g = mt*16+row_;
        float val = acc[j] + bo;
        if (mat){
          memv[(size_t)g*1024 + o] = f2bf(val);
        } else {
          int bb=g/1200, ss=g-bb*1200;
          mt8[(((size_t)(bb*4 + (o>>8))*32 + ((o&255)>>3))*1200 + ss)*8 + (o&7)] = f2bf(val);
        }
      }
    }
  }
}

// ---------------- main sequential loop (plain launch, 256 co-resident blocks) ----------------
struct LoopArgs {
  const float *sa_bq,*sa_bk,*sa_bv,*sa_bo,*ca_bq,*ca_bo,*b_ff1,*b_ff2;
  const float *g1,*be1,*g2,*be2,*g3,*be3;
  char* ws;
};

__global__ void __launch_bounds__(256) k_loop(LoopArgs A){
  __shared__ u16 WL[3*16*1024];      // 96 KB swizzled resident weight slots
  __shared__ u16 SL[16*1032];        // 33 KB staging
  __shared__ float FB[1024];
  __shared__ float PL[608];
  __shared__ float RB[640];
  __shared__ float STm[16], STr[16];

  char* ws = A.ws;
  const u16* wq   =(const u16*)(ws+OFF_WQ);
  const u16* wk   =(const u16*)(ws+OFF_WK);
  const u16* wv_  =(const u16*)(ws+OFF_WV);
  const u16* wo   =(const u16*)(ws+OFF_WO);
  const u16* cawq =(const u16*)(ws+OFF_CAWQ);
  const u16* cawo =(const u16*)(ws+OFF_CAWO);
  const u16* ff1  =(const u16*)(ws+OFF_FF1);
  const u16* ff2  =(const u16*)(ws+OFF_FF2);
  const u16* mb   =(const u16*)(ws+OFF_MB);
  const float* pe =(const float*)(ws+OFF_PE);
  const float* bcomb=(const float*)(ws+OFF_BCOMB);
  const u16* mt8  =(const u16*)(ws+OFF_MEMK);
  const u16* memv =(const u16*)(ws+OFF_MEMV);
  u16* kc =(u16*)(ws+OFF_KC);
  u16* vc =(u16*)(ws+OFF_VC);
  u16* u3s=(u16*)(ws+OFF_U3S);
  float* st3=(float*)(ws+OFF_ST3);
  u16* emb=(u16*)(ws+OFF_EMB);
  u16* qb =(u16*)(ws+OFF_QB);
  u16* sab=(u16*)(ws+OFF_SA);
  u16* u1 =(u16*)(ws+OFF_U1);
  float* st1=(float*)(ws+OFF_ST1);
  u16* q2b=(u16*)(ws+OFF_Q2);
  u16* cab=(u16*)(ws+OFF_CA);
  u16* u2 =(u16*)(ws+OFF_U2);
  float* st2=(float*)(ws+OFF_ST2);
  u16* hh =(u16*)(ws+OFF_HH);
  char* barb=(char*)(ws+OFF_BAR);

  unsigned epoch = 0;
  int wg = blockIdx.x, tid = threadIdx.x;
  int row = tid>>4, lo = tid&15;
  int grp = wg>>6, ct = (wg&63)<<4;

  // ---- one-time: preload weight tiles into LDS (swizzled); cached reads (prep kernel boundary = flush) ----
  {
    u16* s0d = WL;          u16* s1d = WL+16384;  u16* s2d = WL+32768;
    if (grp==0){
      copy_slot(wq  +(size_t)ct*1024,1024,s0d);
      copy_slot(cawq+(size_t)ct*1024,1024,s1d);
      copy_slot(ff1 +(size_t)ct*1024,1024,s2d);
    } else if (grp==1){
      copy_slot(wk  +(size_t)ct*1024,1024,s0d);
      copy_slot(cawo+(size_t)ct*1024,1024,s1d);
      copy_slot(ff1 +((size_t)(1024+ct))*1024,1024,s2d);
    } else if (grp==2){
      copy_slot(wv_ +(size_t)ct*1024,1024,s0d);
      copy_slot(ff2 +(size_t)ct*2048,2048,s1d);
      copy_slot(ff2 +(size_t)ct*2048+1024,2048,s2d);
    } else {
      copy_slot(wo  +(size_t)ct*1024,1024,s0d);
      copy_slot(mb  +(size_t)ct*1024,1024,s1d);
    }
    __syncthreads();
  }
  const u16* SLOT0 = WL;
  const u16* SLOT1 = WL+16384;
  const u16* SLOT2 = WL+32768;

  #pragma unroll 1
  for (int i=0;i<600;i++){
    int ip = i%25;

    // ---- phase A: x = emb + pe ; q/k/v projections (192 wgs) ----
    if (wg < 192){
      { int c0 = lo<<6;
        s16x8 e8[8];
        ld128_dc(emb + row*1024 + c0, e8);
        const float* pp = pe + ip*1024 + c0;
        u16* d = SL + row*1032 + c0;
        #pragma unroll
        for(int c=0;c<8;c++){ s16x8 o;
          #pragma unroll
          for(int j=0;j<8;j++) o[j] = (short)f2bf(bf2f((u16)e8[c][j]) + pp[c*8+j]);
          *(s16x8*)(d+c*8) = o; }
        __syncthreads();
      }
      const float* bias = (grp==0)? A.sa_bq : (grp==1)? A.sa_bk : A.sa_bv;
      float v = gemm_w(SL,1032,SLOT0,FB);
      int o = ct + lo;
      u16 bv = f2bf(v + bias[o]);
      if (grp==0)      st2_dc(qb + row*1024 + o, bv);
      else if (grp==1) st2_dc(kc + ((size_t)i*16+row)*1024 + o, bv);
      else             st2_dc(vc + ((size_t)i*16+row)*1024 + o, bv);
    }
    gbar(barb, epoch);

    // ---- phase B: full self-attn for one (b,h) (64 wgs); all K/V reads device-coherent, batched ----
    if (wg < 64){
      int b=wg>>2, h=wg&3, cnt=i+1;
      RB[tid] = bf2f(ld2_dc(qb + b*1024 + h*256 + tid));
      __syncthreads();
      float sl = 1.0f/(float)(4<<(2*h));
      float mx=-1e30f;
      for(int t=tid; t<cnt; t+=256){
        const u16* kr = kc + ((size_t)t*16 + b)*1024 + h*256;
        s16x8 kb[16];
        float s=0.f;
        ld8_nw(kr, kb); ld8_nw(kr+64, kb+8);
        vmwait0();
        #pragma unroll
        for(int c=0;c<16;c++){
          #pragma unroll
          for(int j=0;j<8;j++) s += RB[c*8+j]*bf2f((u16)kb[c][j]);
        }
        ld8_nw(kr+128, kb); ld8_nw(kr+192, kb+8);
        vmwait0();
        #pragma unroll
        for(int c=0;c<16;c++){
          #pragma unroll
          for(int j=0;j<8;j++) s += RB[128+c*8+j]*bf2f((u16)kb[c][j]);
        }
        s = s*0.0625f - sl*(float)((i-t)/25);
        PL[t]=s; mx=fmaxf(mx,s);
      }
      mx = brmax(mx,RB);
      float ls=0.f;
      for(int t=tid;t<cnt;t+=256){ float e=__expf(PL[t]-mx); PL[t]=e; ls+=e; }
      float l = brsum(ls,RB);
      float rl = 1.0f/l;
      int d_oct = tid>>3, t_ln = tid&7;
      const u16* vcb = vc + (size_t)b*1024 + h*256 + d_oct*8;
      float acc[8]={0.f,0.f,0.f,0.f,0.f,0.f,0.f,0.f};
      for(int base=t_ln; base<cnt; base+=64){
        s16x8 vb[8];
        #pragma unroll
        for(int j=0;j<8;j++){
          int t = base + j*8; size_t tt = (t<cnt)? (size_t)t : 0;
          ld16_nw(vcb + tt*16384, &vb[j]);
        }
        vmwait0();
        #pragma unroll
        for(int j=0;j<8;j++){
          int t = base + j*8;
          float p = (t<cnt)? PL[t] : 0.f;
          #pragma unroll
          for(int jj=0;jj<8;jj++) acc[jj] += p*bf2f((u16)vb[j][jj]);
        }
      }
      #pragma unroll
      for(int j=0;j<8;j++){
        acc[j] += __shfl_xor(acc[j],1);
        acc[j] += __shfl_xor(acc[j],2);
        acc[j] += __shfl_xor(acc[j],4);
      }
      if (t_ln==0){
        s16x8 o8;
        #pragma unroll
        for(int j=0;j<8;j++) o8[j]=(short)f2bf(acc[j]*rl);
        st16_dc(sab + b*1024 + h*256 + d_oct*8, o8);
      }
    }
    gbar(barb, epoch);

    // ---- phase C: u1 = x + sa@Wo^T + bo (wgs 192..255) ----
    if (wg>=192){
      stage16_dc(sab,1024,0,SL);
      float v = gemm_w(SL,1032,SLOT0,FB);
      int o = ct+lo;
      float x = bf2f(ld2_dc(emb + row*1024 + o)) + pe[ip*1024+o];
      st2_dc(u1 + row*1024 + o, f2bf(x + v + A.sa_bo[o]));
    }
    gbar(barb, epoch);

    // ---- phase D: q2 = LN1(u1)@caWq^T + bq (wgs 0..63) ----
    if (wg<64){
      stage_ln16_dc(u1, A.g1, A.be1, SL, RB, STm, STr);
      float v = gemm_w(SL,1032,SLOT1,FB);
      int o=ct+lo;
      st2_dc(q2b + row*1024+o, f2bf(v + A.ca_bq[o]));
      if (wg==0 && tid<16){ stf_dc(st1+tid*2, STm[tid]); stf_dc(st1+tid*2+1, STr[tid]); }
    }
    gbar(barb, epoch);

    // ---- phase E: windowed cross-attn -> ca (wgs 0..63); memk/memv cached (prep-written, immutable) ----
    if (wg<64){
      int b=wg>>2, h=wg&3;
      RB[tid] = bf2f(ld2_dc(q2b + b*1024 + h*256 + tid));
      __syncthreads();
      int s0 = 2*i-6; if(s0<0)s0=0;
      int s1 = 2*i+2; if(s1>1200)s1=1200;
      int ns = s1-s0;
      int si=tid>>5, dl=tid&31;
      float p=0.f;
      if (si<ns){
        const u16* MT = mt8 + (((size_t)(b*4+h)*32 + dl)*1200 + (s0+si))*8;
        s16x8 m8 = *(const s16x8*)MT;
        #pragma unroll
        for(int j=0;j<8;j++) p += RB[dl*8+j]*bf2f((u16)m8[j]);
      }
      #pragma unroll
      for(int o2=16;o2>0;o2>>=1) p += __shfl_xor(p,o2);
      if (dl==0 && si<ns) RB[512+si] = p*0.0625f;
      __syncthreads();
      float mx=-1e30f;
      for(int q=0;q<ns;q++) mx=fmaxf(mx,RB[512+q]);
      float l=0.f, acc=0.f;
      for(int q=0;q<ns;q++){
        float e=__expf(RB[512+q]-mx); l+=e;
        acc += e*bf2f(memv[(size_t)(b*1200+s0+q)*1024 + h*256 + tid]);
      }
      st2_dc(cab + b*1024+h*256+tid, f2bf(acc/l));
    }
    gbar(barb, epoch);

    // ---- phase F: u2 = x1 + ca@caWo^T + bo2 (wgs 64..127) ----
    if (wg>=64 && wg<128){
      stage16_dc(cab,1024,0,SL);
      float v = gemm_w(SL,1032,SLOT1,FB);
      int o=ct+lo;
      f32x2 s1v = ldf2_dc(st1 + row*2);
      float x1 = (bf2f(ld2_dc(u1+row*1024+o))-s1v[0])*s1v[1]*A.g1[o] + A.be1[o];
      st2_dc(u2+row*1024+o, f2bf(x1 + v + A.ca_bo[o]));
    }
    gbar(barb, epoch);

    // ---- phase G: hh = relu(LN2(u2)@FF1^T + b1) (wgs 0..127) ----
    if (wg<128){
      stage_ln16_dc(u2, A.g2, A.be2, SL, RB, STm, STr);
      float v = gemm_w(SL,1032,SLOT2,FB);
      int o=(wg<<4)+lo;
      st2_dc(hh+row*2048+o, f2bf(fmaxf(v + A.b_ff1[o], 0.f)));
      if (wg==0 && tid<16){ stf_dc(st2+tid*2,STm[tid]); stf_dc(st2+tid*2+1,STr[tid]); }
    }
    gbar(barb, epoch);

    // ---- phase H: u3 = x2 + hh@FF2^T + b2 (wgs 128..191; K=2048 via two slots) ----
    if (wg>=128 && wg<192){
      stage16_dc(hh, 2048, 0, SL);
      float v = gemm_w(SL,1032,SLOT1,FB);
      stage16_dc(hh, 2048, 1024, SL);
      v += gemm_w(SL,1032,SLOT2,FB);
      int o=ct+lo;
      f32x2 s2v = ldf2_dc(st2+row*2);
      float x2 = (bf2f(ld2_dc(u2+row*1024+o))-s2v[0])*s2v[1]*A.g2[o] + A.be2[o];
      st2_dc(u3s + ((size_t)i*16+row)*1024+o, f2bf(x2 + v + A.b_ff2[o]));
    }
    gbar(barb, epoch);

    // ---- phase I: emb = LN3(u3)@M^T + bcomb (wgs 192..255) ----
    if (wg>=192){
      stage_ln16_dc(u3s + (size_t)i*16384, A.g3, A.be3, SL, RB, STm, STr);
      float v = gemm_w(SL,1032,SLOT1,FB);
      int o=ct+lo;
      st2_dc(emb+row*1024+o, f2bf(v + bcomb[o]));
      if (wg==192 && tid<16){ st3[i*32+tid*2]=STm[tid]; st3[i*32+tid*2+1]=STr[tid]; }  // read only post-kernel
    }
    gbar(barb, epoch);
  }
}

// ---------------- deferred loss ----------------
__global__ void __launch_bounds__(256) k_loss(const u16* u3s, const float* st3, const u16* wvr,
                                              const float* bvr, const float* g3, const float* be3,
                                              const float* vert, float* loss){
  __shared__ u16 SL[16*1032];
  __shared__ float R[64];
  int bx=blockIdx.x; int ib=bx/11, cb=bx%11;
  int tid=threadIdx.x, wvv=tid>>6, ln=tid&63;
  int r=ln&15, kq=ln>>4;
  float lsum=0.f;
  for(int ii=0;ii<8;ii++){
    int i=ib*8+ii;
    { int row=tid>>4, c0=(tid&15)<<6;
      float m=st3[i*32+row*2], rs=st3[i*32+row*2+1];
      const u16* s=u3s + (size_t)(i*16+row)*1024 + c0;
      u16* d=SL + row*1032 + c0;
      #pragma unroll
      for(int c=0;c<64;c+=8){ s16x8 v=*(const s16x8*)(s+c); s16x8 o;
        #pragma unroll
        for(int j=0;j<8;j++){ int cc=c0+c+j; o[j]=(short)f2bf((bf2f((u16)v[j])-m)*rs*g3[cc]+be3[cc]); }
        *(s16x8*)(d+c)=o; }
      __syncthreads();
    }
    const u16* ap = SL + r*1032 + kq*8;
    for(int rep=0;rep<2;rep++){
      int colb = cb*128 + wvv*32 + rep*16;
      int o_r = colb + r; bool ok = o_r < 1404;
      const u16* bp = wvr + (size_t)(ok? o_r:0)*1024 + kq*8;
      f32x4 acc={0.f,0.f,0.f,0.f};
      for(int k=0;k<1024;k+=32)
        acc = __builtin_amdgcn_mfma_f32_16x16x32_bf16(*(const s16x8*)(ap+k), *(const s16x8*)(bp+k), acc, 0,0,0);
      if (ok){
        float bo = bvr[o_r];
        #pragma unroll
        for(int j=0;j<4;j++){
          int b_=kq*4+j;
          float ov = acc[j] + bo;
          float vt = vert[(size_t)(b_*600 + i)*1404 + o_r];
          float dd = ov - vt; lsum += dd*dd;
        }
      }
    }
    __syncthreads();
  }
  #pragma unroll
  for(int o=32;o>0;o>>=1) lsum += __shfl_down(lsum,o);
  if (ln==0) R[wvv]=lsum;
  __syncthreads();
  if (tid==0) atomicAdd(loss, (R[0]+R[1])+(R[2]+R[3]));
}

__global__ void k_fin(const float* loss, float* dout){
  if (threadIdx.x==0) dout[0] = loss[0] * (1.f/13478400.f);   // / (16*600*1404)
}

// ---------------- host ----------------
extern "C" void kernel_launch(void* const* d_in, const int* in_sizes, int n_in,
                              void* d_out, int out_size, void* d_ws, size_t ws_size,
                              hipStream_t stream){
  char* ws = (char*)d_ws;
  if (ws_size < WS_NEED){ hipMemsetAsync(d_out, 0, 4, stream); return; }

  const float* audio=(const float*)d_in[0];
  const float* vert =(const float*)d_in[1];
  const float* W_af =(const float*)d_in[2];
  const float* b_af =(const float*)d_in[3];
  const float* saWq =(const float*)d_in[4];  const float* sa_bq=(const float*)d_in[5];
  const float* saWk =(const float*)d_in[6];  const float* sa_bk=(const float*)d_in[7];
  const float* saWv =(const float*)d_in[8];  const float* sa_bv=(const float*)d_in[9];
  const float* saWo =(const float*)d_in[10]; const float* sa_bo=(const float*)d_in[11];
  const float* caWq =(const float*)d_in[12]; const float* ca_bq=(const float*)d_in[13];
  const float* caWk =(const float*)d_in[14]; const float* ca_bk=(const float*)d_in[15];
  const float* caWv =(const float*)d_in[16]; const float* ca_bv=(const float*)d_in[17];
  const float* caWo =(const float*)d_in[18]; const float* ca_bo=(const float*)d_in[19];
  const float* g1=(const float*)d_in[20]; const float* be1=(const float*)d_in[21];
  const float* g2=(const float*)d_in[22]; const float* be2=(const float*)d_in[23];
  const float* g3=(const float*)d_in[24]; const float* be3=(const float*)d_in[25];
  const float* Wff1=(const float*)d_in[26]; const float* b_ff1=(const float*)d_in[27];
  const float* Wff2=(const float*)d_in[28]; const float* b_ff2=(const float*)d_in[29];
  const float* Wvm=(const float*)d_in[30];  const float* b_vm=(const float*)d_in[31];
  const float* Wvr=(const float*)d_in[32];  const float* b_vr=(const float*)d_in[33];

  k_init<<<1,256,0,stream>>>(b_vm, (float*)(ws+OFF_PE), (u16*)(ws+OFF_EMB), (float*)(ws+OFF_LOSS), (unsigned*)(ws+OFF_BAR));

  k_f2bf<<<512,256,0,stream>>>(saWq,(u16*)(ws+OFF_WQ),1048576);
  k_f2bf<<<512,256,0,stream>>>(saWk,(u16*)(ws+OFF_WK),1048576);
  k_f2bf<<<512,256,0,stream>>>(saWv,(u16*)(ws+OFF_WV),1048576);
  k_f2bf<<<512,256,0,stream>>>(saWo,(u16*)(ws+OFF_WO),1048576);
  k_f2bf<<<512,256,0,stream>>>(caWq,(u16*)(ws+OFF_CAWQ),1048576);
  k_f2bf<<<512,256,0,stream>>>(caWo,(u16*)(ws+OFF_CAWO),1048576);
  k_f2bf<<<1024,256,0,stream>>>(Wff1,(u16*)(ws+OFF_FF1),2097152);
  k_f2bf<<<1024,256,0,stream>>>(Wff2,(u16*)(ws+OFF_FF2),2097152);
  k_f2bf<<<702,256,0,stream>>>(Wvr,(u16*)(ws+OFF_WVR),1437696);

  k_tr<<<24*32,256,0,stream>>>(W_af, 1024, 768, (u16*)(ws+OFF_WAFT), 1024);
  k_tr<<<32*44,256,0,stream>>>(Wvr, 1404, 1024, (u16*)(ws+OFF_WVRT), 1408);

  k_gemm_pre<<<64*48,256,0,stream>>>(caWk, 1024, 1024, 1024, (const u16*)(ws+OFF_WAFT), (u16*)(ws+OFF_WKP), 768, 48);
  k_gemm_pre<<<64*48,256,0,stream>>>(caWv, 1024, 1024, 1024, (const u16*)(ws+OFF_WAFT), (u16*)(ws+OFF_WVP), 768, 48);
  k_gemm_pre<<<64*64,256,0,stream>>>(Wvm, 1404, 1404, 1408, (const u16*)(ws+OFF_WVRT), (u16*)(ws+OFF_MB), 1024, 64);

  k_bvec<<<12,256,0,stream>>>(caWk, ca_bk, b_af, caWv, ca_bv, Wvm, b_vr, b_vm,
                              (float*)(ws+OFF_BKP),(float*)(ws+OFF_BVP),(float*)(ws+OFF_BCOMB));

  k_mem<<<9600,256,0,stream>>>(audio, (const u16*)(ws+OFF_WKP),(const u16*)(ws+OFF_WVP),
                               (const float*)(ws+OFF_BKP),(const float*)(ws+OFF_BVP),
                               (u16*)(ws+OFF_MEMK),(u16*)(ws+OFF_MEMV));

  LoopArgs la{ sa_bq, sa_bk, sa_bv, sa_bo, ca_bq, ca_bo, b_ff1, b_ff2,
               g1, be1, g2, be2, g3, be3, ws };
  k_loop<<<256,256,0,stream>>>(la);

  k_loss<<<825,256,0,stream>>>((const u16*)(ws+OFF_U3S),(const float*)(ws+OFF_ST3),
                               (const u16*)(ws+OFF_WVR), b_vr, g3, be3, vert, (float*)(ws+OFF_LOSS));
  k_fin<<<1,64,0,stream>>>((const float*)(ws+OFF_LOSS), (float*)d_out);
}

// Round 6
// 45809.601 us; speedup vs baseline: 4.4211x; 1.0028x over previous
//
#include <hip/hip_runtime.h>

typedef unsigned short u16;
typedef short s16x8 __attribute__((ext_vector_type(8)));
typedef float f32x4 __attribute__((ext_vector_type(4)));
typedef float f32x2 __attribute__((ext_vector_type(2)));

#define DEV static __device__ __forceinline__

DEV float bf2f(u16 h){ union{unsigned u;float f;} v; v.u=((unsigned)h)<<16; return v.f; }
DEV u16 f2bf(float f){ union{float f;unsigned u;} v; v.f=f; unsigned u=v.u; return (u16)((u + 0x7fffu + ((u>>16)&1u))>>16); }

// ---------------- device-coherent IO (sc0 sc1: bypass L1/L2 -> coherence point; no fences needed) ----------------
DEV void st2_dc(u16* p, u16 v){
  unsigned vv = v;
  asm volatile("global_store_short %0, %1, off sc0 sc1" :: "v"(p), "v"(vv) : "memory");
}
DEV void st16_dc(void* p, s16x8 v){
  asm volatile("global_store_dwordx4 %0, %1, off sc0 sc1" :: "v"(p), "v"(v) : "memory");
}
DEV void stf_dc(float* p, float v){
  asm volatile("global_store_dword %0, %1, off sc0 sc1" :: "v"(p), "v"(v) : "memory");
}
DEV u16 ld2_dc(const u16* p){
  unsigned r;
  asm volatile("global_load_ushort %0, %1, off sc0 sc1\n\ts_waitcnt vmcnt(0)" : "=&v"(r) : "v"(p) : "memory");
  return (u16)r;
}
DEV f32x2 ldf2_dc(const float* p){
  f32x2 r;
  asm volatile("global_load_dwordx2 %0, %1, off sc0 sc1\n\ts_waitcnt vmcnt(0)" : "=&v"(r) : "v"(p) : "memory");
  return r;
}
// single 16B coherent load, NO wait (issue-only); single-instruction asm cannot alias-corrupt
#define LD16O(dst, p, OFFSTR) \
  asm volatile("global_load_dwordx4 %0, %1, off offset:" OFFSTR " sc0 sc1" : "=&v"(dst) : "v"(p) : "memory")
DEV void vmwait0(){ asm volatile("s_waitcnt vmcnt(0)" ::: "memory"); }
// 8 x 16B in flight (128B), no wait
DEV void ld8_nw(const u16* p, s16x8* o){
  LD16O(o[0],p,"0");  LD16O(o[1],p,"16"); LD16O(o[2],p,"32"); LD16O(o[3],p,"48");
  LD16O(o[4],p,"64"); LD16O(o[5],p,"80"); LD16O(o[6],p,"96"); LD16O(o[7],p,"112");
}
DEV void ld128_dc(const u16* p, s16x8* o){ ld8_nw(p,o); vmwait0(); }

// ---------------- workspace layout (bytes) ----------------
constexpr size_t SZ_DD = (size_t)1024*1024*2;
constexpr size_t OFF_WQ=0;
constexpr size_t OFF_WK=OFF_WQ+SZ_DD;
constexpr size_t OFF_WV=OFF_WK+SZ_DD;
constexpr size_t OFF_WO=OFF_WV+SZ_DD;
constexpr size_t OFF_CAWQ=OFF_WO+SZ_DD;
constexpr size_t OFF_CAWO=OFF_CAWQ+SZ_DD;
constexpr size_t OFF_FF1=OFF_CAWO+SZ_DD;                    // 2048x1024 bf16
constexpr size_t OFF_FF2=OFF_FF1+(size_t)2048*1024*2;       // 1024 rows x 2048 K bf16
constexpr size_t OFF_MB =OFF_FF2+(size_t)2048*1024*2;       // 1024x1024 bf16 (Wvm@Wvr)
constexpr size_t OFF_WVR=OFF_MB+SZ_DD;                      // 1404x1024 bf16
constexpr size_t OFF_WKP=OFF_WVR+(size_t)1404*1024*2;       // 1024x768 bf16
constexpr size_t OFF_WVP=OFF_WKP+(size_t)1024*768*2;
constexpr size_t OFF_WAFT=OFF_WVP+(size_t)1024*768*2;       // 768x1024 bf16 (W_af^T)
constexpr size_t OFF_WVRT=OFF_WAFT+(size_t)768*1024*2;      // 1024x1408 bf16 (Wvr^T padded)
constexpr size_t OFF_PE  =OFF_WVRT+(size_t)1024*1408*2;     // 25x1024 f32
constexpr size_t OFF_BKP =OFF_PE+25*1024*4;                 // 1024 f32
constexpr size_t OFF_BVP =OFF_BKP+4096;
constexpr size_t OFF_BCOMB=OFF_BVP+4096;
constexpr size_t OFF_MEMK=OFF_BCOMB+4096;                   // oct layout [16][4][32][1200][8] bf16
constexpr size_t OFF_MEMV=OFF_MEMK+(size_t)16*1200*1024*2;  // [b*1200+s][1024]
constexpr size_t OFF_KC  =OFF_MEMV+(size_t)16*1200*1024*2;  // [(t*16+b)][1024] bf16 (write-once slots)
constexpr size_t OFF_VC  =OFF_KC+(size_t)600*16*1024*2;
constexpr size_t OFF_U3S =OFF_VC+(size_t)600*16*1024*2;     // 600x16x1024 bf16
constexpr size_t OFF_ST3 =OFF_U3S+(size_t)600*16*1024*2;    // 600x16x2 f32
constexpr size_t OFF_EMB =OFF_ST3+600*32*4;                 // 16x1024 bf16
constexpr size_t OFF_QB  =OFF_EMB+32768;
constexpr size_t OFF_SC  =OFF_QB+32768;                     // (reserved)
constexpr size_t OFF_SA  =OFF_SC+(size_t)16*4*608*4;
constexpr size_t OFF_U1  =OFF_SA+32768;
constexpr size_t OFF_ST1 =OFF_U1+32768;                     // 32 f32
constexpr size_t OFF_Q2  =OFF_ST1+256;
constexpr size_t OFF_CA  =OFF_Q2+32768;
constexpr size_t OFF_U2  =OFF_CA+32768;
constexpr size_t OFF_ST2 =OFF_U2+32768;
constexpr size_t OFF_HH  =OFF_ST2+256;                      // 16x2048 bf16
constexpr size_t OFF_LOSS=OFF_HH+65536;
constexpr size_t OFF_BAR =OFF_LOSS+256;                     // 32 x 256B barrier lines (16 leaf + 16 leafdone)
constexpr size_t WS_NEED =OFF_BAR+8192;

// ---------------- shared helpers ----------------
DEV float brmax(float v, float* R){
  #pragma unroll
  for(int o=32;o>0;o>>=1) v = fmaxf(v, __shfl_down(v,o));
  if ((threadIdx.x&63)==0) R[576+(threadIdx.x>>6)] = v;
  __syncthreads();
  v = fmaxf(fmaxf(R[576],R[577]), fmaxf(R[578],R[579]));
  __syncthreads();
  return v;
}
DEV float brsum(float v, float* R){
  #pragma unroll
  for(int o=32;o>0;o>>=1) v += __shfl_down(v,o);
  if ((threadIdx.x&63)==0) R[580+(threadIdx.x>>6)] = v;
  __syncthreads();
  v = (R[580]+R[581])+(R[582]+R[583]);
  __syncthreads();
  return v;
}

// GEMM 16x16 tile: A from SL (stride lds_stride), B from swizzled LDS weight slot
DEV float gemm_w(const u16* SLu, int lds_stride, const u16* slot, float* FB){
  int tid=threadIdx.x, wv=tid>>6, ln=tid&63;
  int r=ln&15, kq=ln>>4;
  int k0=wv*256 + kq*8;
  const u16* ap = SLu + r*lds_stride + k0;
  int sw=(r&7)<<3;
  const u16* bp = slot + r*1024;
  f32x4 acc={0.f,0.f,0.f,0.f};
  #pragma unroll
  for(int k=0;k<1024;k+=128)
    acc = __builtin_amdgcn_mfma_f32_16x16x32_bf16(*(const s16x8*)(ap+(k>>2)),
                                                  *(const s16x8*)(bp + (((k0+(k>>2)))^sw)), acc, 0,0,0);
  #pragma unroll
  for(int j=0;j<4;j++) FB[wv*256 + (kq*4+j)*16 + r] = acc[j];
  __syncthreads();
  int row=tid>>4, col=tid&15;
  float s=(FB[row*16+col]+FB[256+row*16+col])+(FB[512+row*16+col]+FB[768+row*16+col]);
  __syncthreads();
  return s;
}

// copy one 16x1024 bf16 weight tile (global, row stride rstride) into swizzled LDS slot (cached reads: prep-written)
DEV void copy_slot(const u16* src, int rstride, u16* dst){
  int row=threadIdx.x>>4, k0=(threadIdx.x&15)<<6;
  int sw=(row&7)<<3;
  const u16* s = src + (size_t)row*rstride + k0;
  u16* d = dst + row*1024;
  #pragma unroll
  for(int c=0;c<64;c+=8)
    *(s16x8*)(d + (((k0+c))^sw)) = *(const s16x8*)(s+c);
}

// stage 16x1024 via device-coherent loads into SL[16][1032]
DEV void stage16_dc(const u16* src, int srcstride, int c0base, u16* SL){
  int row=threadIdx.x>>4, c0=(threadIdx.x&15)<<6;
  s16x8 o[8];
  ld128_dc(src + (size_t)row*srcstride + c0base + c0, o);
  u16* d=SL+row*1032+c0;
  #pragma unroll
  for(int c=0;c<8;c++) *(s16x8*)(d+c*8) = o[c];
  __syncthreads();
}

// stage u (16x1024, device-coherent) applying LayerNorm(g,be); stats in STm/STr.
DEV void stage_ln16_dc(const u16* u, const float* g, const float* be, u16* SL, float* RB, float* STm, float* STr){
  int tid=threadIdx.x; int row=tid>>4, c0=(tid&15)<<6;
  s16x8 vr[8];
  ld128_dc(u + (size_t)row*1024 + c0, vr);
  float sum=0.f, sq=0.f;
  #pragma unroll
  for(int c=0;c<8;c++){
    #pragma unroll
    for(int j=0;j<8;j++){ float f=bf2f((u16)vr[c][j]); sum+=f; sq+=f*f; }
  }
  RB[tid]=sum; RB[256+tid]=sq;
  __syncthreads();
  if (tid<16){
    float S=0.f,Q=0.f;
    #pragma unroll
    for(int k=0;k<16;k++){ S+=RB[tid*16+k]; Q+=RB[256+tid*16+k]; }
    float m=S*(1.f/1024.f); float var=Q*(1.f/1024.f)-m*m;
    STm[tid]=m; STr[tid]=rsqrtf(var+1e-5f);
  }
  __syncthreads();
  float m=STm[row], rs=STr[row];
  u16* d = SL + row*1032 + c0;
  #pragma unroll
  for(int c=0;c<8;c++){
    s16x8 o;
    #pragma unroll
    for(int j=0;j<8;j++){ int cc=c0+c*8+j; float f=(bf2f((u16)vr[c][j])-m)*rs*g[cc]+be[cc]; o[j]=(short)f2bf(f); }
    *(s16x8*)(d + c*8) = o;
  }
  __syncthreads();
}

// grid barrier: NO fences. vmcnt drains each wave's sc0sc1 stores.
// 16 leaf counters (RMW, 16 blocks each); leaf winners publish leafdone[l]; all blocks poll 16 slots concurrently.
DEV void gbar(char* barb, unsigned& epoch){
  vmwait0();
  __syncthreads();
  unsigned target = epoch + 1u;
  if (threadIdx.x == 0){
    unsigned* leaf = (unsigned*)(barb + ((blockIdx.x & 15) << 8));
    unsigned prev = __hip_atomic_fetch_add(leaf, 1u, __ATOMIC_RELAXED, __HIP_MEMORY_SCOPE_AGENT);
    if (prev == epoch*16u + 15u){
      unsigned* done = (unsigned*)(barb + ((16 + (blockIdx.x & 15)) << 8));
      __hip_atomic_store(done, target, __ATOMIC_RELAXED, __HIP_MEMORY_SCOPE_AGENT);
    }
  }
  if (threadIdx.x < 16){
    unsigned* done = (unsigned*)(barb + ((16 + threadIdx.x) << 8));
    while (__hip_atomic_load(done, __ATOMIC_RELAXED, __HIP_MEMORY_SCOPE_AGENT) < target)
      __builtin_amdgcn_s_sleep(1);
  }
  __syncthreads();
  epoch++;
}

// ---------------- prep kernels ----------------
__global__ void __launch_bounds__(256) k_init(const float* b_vm, float* pe, u16* emb, float* loss, unsigned* bar){
  int tid=threadIdx.x;
  if (tid==0) loss[0]=0.f;
  for(int idx=tid; idx<2048; idx+=256) bar[idx]=0u;
  for(int idx=tid; idx<16384; idx+=256) emb[idx] = f2bf(b_vm[idx&1023]);
  for(int idx=tid; idx<25600; idx+=256){
    int p_=idx>>10, d_=idx&1023; int m=d_>>1;
    float div = expf(-(float)(2*m) * (9.210340372f/1024.f));
    float a = (float)p_ * div;
    pe[idx] = (d_&1)? cosf(a) : sinf(a);
  }
}

__global__ void __launch_bounds__(256) k_f2bf(const float* s, u16* d, int n){
  int idx=(blockIdx.x*256+threadIdx.x)*8;
  if (idx < n){
    #pragma unroll
    for(int j=0;j<8;j++) d[idx+j]=f2bf(s[idx+j]);
  }
}

__global__ void __launch_bounds__(256) k_tr(const float* src, int R, int C, u16* dst, int ldd){
  __shared__ float TL[32][33];
  int cb=(C+31)/32;
  int bj=blockIdx.x%cb, br=blockIdx.x/cb;
  int j0=bj*32, r0=br*32;
  int lj=threadIdx.x&31, lr=threadIdx.x>>5;
  #pragma unroll
  for(int p=0;p<4;p++){ int rr=r0+lr+p*8, jj=j0+lj;
    TL[lr+p*8][lj] = (rr<R && jj<C)? src[(size_t)rr*C+jj] : 0.f; }
  __syncthreads();
  #pragma unroll
  for(int p=0;p<4;p++){ int jj=j0+lr+p*8, rr=r0+lj;
    if (jj<C && rr<ldd) dst[(size_t)jj*ldd+rr] = f2bf(TL[lj][lr+p*8]); }
}

DEV float gemm_tile16g(const u16* SLu, int lds_stride, const u16* W, int Kext, int wstride, int colbase, float* FB){
  int tid=threadIdx.x, wv=tid>>6, ln=tid&63;
  int r=ln&15, kq=ln>>4;
  int kpw=Kext>>2, k0=wv*kpw;
  const u16* ap = SLu + r*lds_stride + k0 + kq*8;
  const u16* bp = W + (size_t)(colbase+r)*wstride + k0 + kq*8;
  f32x4 acc={0.f,0.f,0.f,0.f};
  for(int k=0;k<kpw;k+=32)
    acc = __builtin_amdgcn_mfma_f32_16x16x32_bf16(*(const s16x8*)(ap+k), *(const s16x8*)(bp+k), acc, 0,0,0);
  #pragma unroll
  for(int j=0;j<4;j++) FB[wv*256 + (kq*4+j)*16 + r] = acc[j];
  __syncthreads();
  int row=tid>>4, col=tid&15;
  float s=(FB[row*16+col]+FB[256+row*16+col])+(FB[512+row*16+col]+FB[768+row*16+col]);
  __syncthreads();
  return s;
}

__global__ void __launch_bounds__(256) k_gemm_pre(const float* A, int lda, int Kreal, int Kpad,
                                                  const u16* Bw, u16* out, int ldo, int Ntiles){
  __shared__ u16 SL[16*1416];
  __shared__ float FB[1024];
  int bx=blockIdx.x; int mt=bx/Ntiles, nt=bx%Ntiles;
  int tid=threadIdx.x;
  int cpt = Kpad>>4;
  { int row=tid>>4, c0=(tid&15)*cpt;
    const float* s=A + (size_t)(mt*16+row)*lda;
    u16* d=SL + row*(Kpad+8);
    for(int c=0;c<cpt;c++){ int k=c0+c; d[k] = (k<Kreal)? f2bf(s[k]) : (u16)0; }
    __syncthreads();
  }
  float v = gemm_tile16g(SL, Kpad+8, Bw, Kpad, Kpad, nt*16, FB);
  int row=tid>>4, col=tid&15;
  out[(size_t)(mt*16+row)*ldo + nt*16+col] = f2bf(v);
}

__global__ void __launch_bounds__(256) k_bvec(const float* caWk, const float* ca_bk, const float* b_af,
                                              const float* caWv, const float* ca_bv,
                                              const float* Wvm, const float* b_vr, const float* b_vm,
                                              float* bkp, float* bvp, float* bcomb){
  __shared__ float VB[1408];
  int seg=blockIdx.x>>2, ch=blockIdx.x&3; int o=ch*256+threadIdx.x;
  const float* vec = (seg==2)? b_vr : b_af; int K = (seg==2)?1404:1024;
  for(int k=threadIdx.x;k<K;k+=256) VB[k]=vec[k];
  __syncthreads();
  const float* Arow = (seg==0)? caWk+(size_t)o*1024 : (seg==1)? caWv+(size_t)o*1024 : Wvm+(size_t)o*1404;
  float s=0.f;
  for(int k=0;k<K;k++) s += Arow[k]*VB[k];
  if(seg==0) bkp[o]=s+ca_bk[o]; else if(seg==1) bvp[o]=s+ca_bv[o]; else bcomb[o]=s+b_vm[o];
}

// mem_k (oct layout) / mem_v (normal) = audio @ Wk'/Wv'^T + bias
__global__ void __launch_bounds__(256) k_mem(const float* audio, const u16* wkp, const u16* wvp,
                                             const float* bkp, const float* bvp, u16* mt8, u16* memv){
  __shared__ u16 SL[16*776];
  int bx=blockIdx.x; int mt=bx>>3, cbk=bx&7;
  int tid=threadIdx.x, wv=tid>>6, ln=tid&63;
  { int row=tid>>4, c0=(tid&15)*48;
    const float* s = audio + (size_t)(mt*16+row)*768 + c0;
    u16* d = SL + row*776 + c0;
    #pragma unroll
    for(int c=0;c<48;c+=8){ s16x8 o;
      #pragma unroll
      for(int j=0;j<8;j++) o[j]=(short)f2bf(s[c+j]);
      *(s16x8*)(d+c)=o; }
    __syncthreads();
  }
  int r=ln&15, kq=ln>>4;
  const u16* ap = SL + r*776 + kq*8;
  for(int rep=0;rep<2;rep++){
    int colb = cbk*128 + wv*32 + rep*16;
    for(int mat=0;mat<2;mat++){
      const u16* W = mat? wvp : wkp;
      const u16* bp = W + (size_t)(colb+r)*768 + kq*8;
      f32x4 acc={0.f,0.f,0.f,0.f};
      for(int k=0;k<768;k+=32)
        acc = __builtin_amdgcn_mfma_f32_16x16x32_bf16(*(const s16x8*)(ap+k), *(const s16x8*)(bp+k), acc, 0,0,0);
      const float* bias = mat? bvp:bkp;
      int o = colb + r;
      float bo = bias[o];
      #pragma unroll
      for(int j=0;j<4;j++){ int row_=kq*4+j;
        int g = mt*16+row_;
        float val = acc[j] + bo;
        if (mat){
          memv[(size_t)g*1024 + o] = f2bf(val);
        } else {
          int bb=g/1200, ss=g-bb*1200;
          mt8[(((size_t)(bb*4 + (o>>8))*32 + ((o&255)>>3))*1200 + ss)*8 + (o&7)] = f2bf(val);
        }
      }
    }
  }
}

// ---------------- main sequential loop (plain launch, 256 co-resident blocks) ----------------
struct LoopArgs {
  const float *sa_bq,*sa_bk,*sa_bv,*sa_bo,*ca_bq,*ca_bo,*b_ff1,*b_ff2;
  const float *g1,*be1,*g2,*be2,*g3,*be3;
  char* ws;
};

__global__ void __launch_bounds__(256) k_loop(LoopArgs A){
  __shared__ u16 WL[3*16*1024];      // 96 KB swizzled resident weight slots
  __shared__ u16 SL[16*1032];        // 33 KB staging
  __shared__ float FB[1024];
  __shared__ float PL[608];
  __shared__ float RB[640];
  __shared__ float STm[16], STr[16];

  char* ws = A.ws;
  const u16* wq   =(const u16*)(ws+OFF_WQ);
  const u16* wk   =(const u16*)(ws+OFF_WK);
  const u16* wv_  =(const u16*)(ws+OFF_WV);
  const u16* wo   =(const u16*)(ws+OFF_WO);
  const u16* cawq =(const u16*)(ws+OFF_CAWQ);
  const u16* cawo =(const u16*)(ws+OFF_CAWO);
  const u16* ff1  =(const u16*)(ws+OFF_FF1);
  const u16* ff2  =(const u16*)(ws+OFF_FF2);
  const u16* mb   =(const u16*)(ws+OFF_MB);
  const float* pe =(const float*)(ws+OFF_PE);
  const float* bcomb=(const float*)(ws+OFF_BCOMB);
  const u16* mt8  =(const u16*)(ws+OFF_MEMK);
  const u16* memv =(const u16*)(ws+OFF_MEMV);
  u16* kc =(u16*)(ws+OFF_KC);
  u16* vc =(u16*)(ws+OFF_VC);
  u16* u3s=(u16*)(ws+OFF_U3S);
  float* st3=(float*)(ws+OFF_ST3);
  u16* emb=(u16*)(ws+OFF_EMB);
  u16* qb =(u16*)(ws+OFF_QB);
  u16* sab=(u16*)(ws+OFF_SA);
  u16* u1 =(u16*)(ws+OFF_U1);
  float* st1=(float*)(ws+OFF_ST1);
  u16* q2b=(u16*)(ws+OFF_Q2);
  u16* cab=(u16*)(ws+OFF_CA);
  u16* u2 =(u16*)(ws+OFF_U2);
  float* st2=(float*)(ws+OFF_ST2);
  u16* hh =(u16*)(ws+OFF_HH);
  char* barb=(char*)(ws+OFF_BAR);

  unsigned epoch = 0;
  int wg = blockIdx.x, tid = threadIdx.x;
  int row = tid>>4, lo = tid&15;
  int grp = wg>>6, ct = (wg&63)<<4;

  // ---- one-time: preload weight tiles into LDS (swizzled); cached reads (prep kernel boundary = flush) ----
  {
    u16* s0d = WL;          u16* s1d = WL+16384;  u16* s2d = WL+32768;
    if (grp==0){
      copy_slot(wq  +(size_t)ct*1024,1024,s0d);
      copy_slot(cawq+(size_t)ct*1024,1024,s1d);
      copy_slot(ff1 +(size_t)ct*1024,1024,s2d);
    } else if (grp==1){
      copy_slot(wk  +(size_t)ct*1024,1024,s0d);
      copy_slot(cawo+(size_t)ct*1024,1024,s1d);
      copy_slot(ff1 +((size_t)(1024+ct))*1024,1024,s2d);
    } else if (grp==2){
      copy_slot(wv_ +(size_t)ct*1024,1024,s0d);
      copy_slot(ff2 +(size_t)ct*2048,2048,s1d);
      copy_slot(ff2 +(size_t)ct*2048+1024,2048,s2d);
    } else {
      copy_slot(wo  +(size_t)ct*1024,1024,s0d);
      copy_slot(mb  +(size_t)ct*1024,1024,s1d);
    }
    __syncthreads();
  }
  const u16* SLOT0 = WL;
  const u16* SLOT1 = WL+16384;
  const u16* SLOT2 = WL+32768;

  #pragma unroll 1
  for (int i=0;i<600;i++){
    int ip = i%25;

    // ---- phase A: x = emb + pe ; q/k/v projections (192 wgs) ----
    if (wg < 192){
      { int c0 = lo<<6;
        s16x8 e8[8];
        ld128_dc(emb + row*1024 + c0, e8);
        const float* pp = pe + ip*1024 + c0;
        u16* d = SL + row*1032 + c0;
        #pragma unroll
        for(int c=0;c<8;c++){ s16x8 o;
          #pragma unroll
          for(int j=0;j<8;j++) o[j] = (short)f2bf(bf2f((u16)e8[c][j]) + pp[c*8+j]);
          *(s16x8*)(d+c*8) = o; }
        __syncthreads();
      }
      const float* bias = (grp==0)? A.sa_bq : (grp==1)? A.sa_bk : A.sa_bv;
      float v = gemm_w(SL,1032,SLOT0,FB);
      int o = ct + lo;
      u16 bv = f2bf(v + bias[o]);
      if (grp==0)      st2_dc(qb + row*1024 + o, bv);
      else if (grp==1) st2_dc(kc + ((size_t)i*16+row)*1024 + o, bv);
      else             st2_dc(vc + ((size_t)i*16+row)*1024 + o, bv);
    }
    gbar(barb, epoch);

    // ---- phase B: full self-attn for one (b,h) (64 wgs) ----
    // K/V slots are WRITE-ONCE (slot t final before first read at iter>=t; 128B-line-exclusive
    // per (b,h) slice; no HW prefetch) -> plain CACHED reads are safe and L1/L2-resident.
    if (wg < 64){
      int b=wg>>2, h=wg&3, cnt=i+1;
      RB[tid] = bf2f(ld2_dc(qb + b*1024 + h*256 + tid));
      __syncthreads();
      float sl = 1.0f/(float)(4<<(2*h));
      float mx=-1e30f;
      for(int t=tid; t<cnt; t+=256){
        const u16* kr = kc + ((size_t)t*16 + b)*1024 + h*256;
        float s=0.f;
        #pragma unroll
        for(int c=0;c<256;c+=8){
          s16x8 k8 = *(const s16x8*)(kr+c);
          #pragma unroll
          for(int j=0;j<8;j++) s += RB[c+j]*bf2f((u16)k8[j]);
        }
        s = s*0.0625f - sl*(float)((i-t)/25);
        PL[t]=s; mx=fmaxf(mx,s);
      }
      mx = brmax(mx,RB);
      float ls=0.f;
      for(int t=tid;t<cnt;t+=256){ float e=__expf(PL[t]-mx); PL[t]=e; ls+=e; }
      float l = brsum(ls,RB);
      float rl = 1.0f/l;
      int d_oct = tid>>3, t_ln = tid&7;
      const u16* vcb = vc + (size_t)b*1024 + h*256 + d_oct*8;
      float acc[8]={0.f,0.f,0.f,0.f,0.f,0.f,0.f,0.f};
      for(int t=t_ln; t<cnt; t+=8){
        s16x8 v8 = *(const s16x8*)(vcb + (size_t)t*16384);
        float p = PL[t];
        #pragma unroll
        for(int jj=0;jj<8;jj++) acc[jj] += p*bf2f((u16)v8[jj]);
      }
      #pragma unroll
      for(int j=0;j<8;j++){
        acc[j] += __shfl_xor(acc[j],1);
        acc[j] += __shfl_xor(acc[j],2);
        acc[j] += __shfl_xor(acc[j],4);
      }
      if (t_ln==0){
        s16x8 o8;
        #pragma unroll
        for(int j=0;j<8;j++) o8[j]=(short)f2bf(acc[j]*rl);
        st16_dc(sab + b*1024 + h*256 + d_oct*8, o8);
      }
    }
    gbar(barb, epoch);

    // ---- phase C: u1 = x + sa@Wo^T + bo (wgs 192..255) ----
    if (wg>=192){
      stage16_dc(sab,1024,0,SL);
      float v = gemm_w(SL,1032,SLOT0,FB);
      int o = ct+lo;
      float x = bf2f(ld2_dc(emb + row*1024 + o)) + pe[ip*1024+o];
      st2_dc(u1 + row*1024 + o, f2bf(x + v + A.sa_bo[o]));
    }
    gbar(barb, epoch);

    // ---- phase D: q2 = LN1(u1)@caWq^T + bq (wgs 0..63) ----
    if (wg<64){
      stage_ln16_dc(u1, A.g1, A.be1, SL, RB, STm, STr);
      float v = gemm_w(SL,1032,SLOT1,FB);
      int o=ct+lo;
      st2_dc(q2b + row*1024+o, f2bf(v + A.ca_bq[o]));
      if (wg==0 && tid<16){ stf_dc(st1+tid*2, STm[tid]); stf_dc(st1+tid*2+1, STr[tid]); }
    }
    gbar(barb, epoch);

    // ---- phase E: windowed cross-attn -> ca (wgs 0..63); memk/memv cached (prep-written, immutable) ----
    if (wg<64){
      int b=wg>>2, h=wg&3;
      RB[tid] = bf2f(ld2_dc(q2b + b*1024 + h*256 + tid));
      __syncthreads();
      int s0 = 2*i-6; if(s0<0)s0=0;
      int s1 = 2*i+2; if(s1>1200)s1=1200;
      int ns = s1-s0;
      int si=tid>>5, dl=tid&31;
      float p=0.f;
      if (si<ns){
        const u16* MT = mt8 + (((size_t)(b*4+h)*32 + dl)*1200 + (s0+si))*8;
        s16x8 m8 = *(const s16x8*)MT;
        #pragma unroll
        for(int j=0;j<8;j++) p += RB[dl*8+j]*bf2f((u16)m8[j]);
      }
      #pragma unroll
      for(int o2=16;o2>0;o2>>=1) p += __shfl_xor(p,o2);
      if (dl==0 && si<ns) RB[512+si] = p*0.0625f;
      __syncthreads();
      float mx=-1e30f;
      for(int q=0;q<ns;q++) mx=fmaxf(mx,RB[512+q]);
      float l=0.f, acc=0.f;
      for(int q=0;q<ns;q++){
        float e=__expf(RB[512+q]-mx); l+=e;
        acc += e*bf2f(memv[(size_t)(b*1200+s0+q)*1024 + h*256 + tid]);
      }
      st2_dc(cab + b*1024+h*256+tid, f2bf(acc/l));
    }
    gbar(barb, epoch);

    // ---- phase F: u2 = x1 + ca@caWo^T + bo2 (wgs 64..127) ----
    if (wg>=64 && wg<128){
      stage16_dc(cab,1024,0,SL);
      float v = gemm_w(SL,1032,SLOT1,FB);
      int o=ct+lo;
      f32x2 s1v = ldf2_dc(st1 + row*2);
      float x1 = (bf2f(ld2_dc(u1+row*1024+o))-s1v[0])*s1v[1]*A.g1[o] + A.be1[o];
      st2_dc(u2+row*1024+o, f2bf(x1 + v + A.ca_bo[o]));
    }
    gbar(barb, epoch);

    // ---- phase G: hh = relu(LN2(u2)@FF1^T + b1) (wgs 0..127) ----
    if (wg<128){
      stage_ln16_dc(u2, A.g2, A.be2, SL, RB, STm, STr);
      float v = gemm_w(SL,1032,SLOT2,FB);
      int o=(wg<<4)+lo;
      st2_dc(hh+row*2048+o, f2bf(fmaxf(v + A.b_ff1[o], 0.f)));
      if (wg==0 && tid<16){ stf_dc(st2+tid*2,STm[tid]); stf_dc(st2+tid*2+1,STr[tid]); }
    }
    gbar(barb, epoch);

    // ---- phase H: u3 = x2 + hh@FF2^T + b2 (wgs 128..191; K=2048 via two slots) ----
    if (wg>=128 && wg<192){
      stage16_dc(hh, 2048, 0, SL);
      float v = gemm_w(SL,1032,SLOT1,FB);
      stage16_dc(hh, 2048, 1024, SL);
      v += gemm_w(SL,1032,SLOT2,FB);
      int o=ct+lo;
      f32x2 s2v = ldf2_dc(st2+row*2);
      float x2 = (bf2f(ld2_dc(u2+row*1024+o))-s2v[0])*s2v[1]*A.g2[o] + A.be2[o];
      st2_dc(u3s + ((size_t)i*16+row)*1024+o, f2bf(x2 + v + A.b_ff2[o]));
    }
    gbar(barb, epoch);

    // ---- phase I: emb = LN3(u3)@M^T + bcomb (wgs 192..255) ----
    if (wg>=192){
      stage_ln16_dc(u3s + (size_t)i*16384, A.g3, A.be3, SL, RB, STm, STr);
      float v = gemm_w(SL,1032,SLOT1,FB);
      int o=ct+lo;
      st2_dc(emb+row*1024+o, f2bf(v + bcomb[o]));
      if (wg==192 && tid<16){ st3[i*32+tid*2]=STm[tid]; st3[i*32+tid*2+1]=STr[tid]; }  // read only post-kernel
    }
    gbar(barb, epoch);
  }
}

// ---------------- deferred loss ----------------
__global__ void __launch_bounds__(256) k_loss(const u16* u3s, const float* st3, const u16* wvr,
                                              const float* bvr, const float* g3, const float* be3,
                                              const float* vert, float* loss){
  __shared__ u16 SL[16*1032];
  __shared__ float R[64];
  int bx=blockIdx.x; int ib=bx/11, cb=bx%11;
  int tid=threadIdx.x, wvv=tid>>6, ln=tid&63;
  int r=ln&15, kq=ln>>4;
  float lsum=0.f;
  for(int ii=0;ii<8;ii++){
    int i=ib*8+ii;
    { int row=tid>>4, c0=(tid&15)<<6;
      float m=st3[i*32+row*2], rs=st3[i*32+row*2+1];
      const u16* s=u3s + (size_t)(i*16+row)*1024 + c0;
      u16* d=SL + row*1032 + c0;
      #pragma unroll
      for(int c=0;c<64;c+=8){ s16x8 v=*(const s16x8*)(s+c); s16x8 o;
        #pragma unroll
        for(int j=0;j<8;j++){ int cc=c0+c+j; o[j]=(short)f2bf((bf2f((u16)v[j])-m)*rs*g3[cc]+be3[cc]); }
        *(s16x8*)(d+c)=o; }
      __syncthreads();
    }
    const u16* ap = SL + r*1032 + kq*8;
    for(int rep=0;rep<2;rep++){
      int colb = cb*128 + wvv*32 + rep*16;
      int o_r = colb + r; bool ok = o_r < 1404;
      const u16* bp = wvr + (size_t)(ok? o_r:0)*1024 + kq*8;
      f32x4 acc={0.f,0.f,0.f,0.f};
      for(int k=0;k<1024;k+=32)
        acc = __builtin_amdgcn_mfma_f32_16x16x32_bf16(*(const s16x8*)(ap+k), *(const s16x8*)(bp+k), acc, 0,0,0);
      if (ok){
        float bo = bvr[o_r];
        #pragma unroll
        for(int j=0;j<4;j++){
          int b_=kq*4+j;
          float ov = acc[j] + bo;
          float vt = vert[(size_t)(b_*600 + i)*1404 + o_r];
          float dd = ov - vt; lsum += dd*dd;
        }
      }
    }
    __syncthreads();
  }
  #pragma unroll
  for(int o=32;o>0;o>>=1) lsum += __shfl_down(lsum,o);
  if (ln==0) R[wvv]=lsum;
  __syncthreads();
  if (tid==0) atomicAdd(loss, (R[0]+R[1])+(R[2]+R[3]));
}

__global__ void k_fin(const float* loss, float* dout){
  if (threadIdx.x==0) dout[0] = loss[0] * (1.f/13478400.f);   // / (16*600*1404)
}

// ---------------- host ----------------
extern "C" void kernel_launch(void* const* d_in, const int* in_sizes, int n_in,
                              void* d_out, int out_size, void* d_ws, size_t ws_size,
                              hipStream_t stream){
  char* ws = (char*)d_ws;
  if (ws_size < WS_NEED){ hipMemsetAsync(d_out, 0, 4, stream); return; }

  const float* audio=(const float*)d_in[0];
  const float* vert =(const float*)d_in[1];
  const float* W_af =(const float*)d_in[2];
  const float* b_af =(const float*)d_in[3];
  const float* saWq =(const float*)d_in[4];  const float* sa_bq=(const float*)d_in[5];
  const float* saWk =(const float*)d_in[6];  const float* sa_bk=(const float*)d_in[7];
  const float* saWv =(const float*)d_in[8];  const float* sa_bv=(const float*)d_in[9];
  const float* saWo =(const float*)d_in[10]; const float* sa_bo=(const float*)d_in[11];
  const float* caWq =(const float*)d_in[12]; const float* ca_bq=(const float*)d_in[13];
  const float* caWk =(const float*)d_in[14]; const float* ca_bk=(const float*)d_in[15];
  const float* caWv =(const float*)d_in[16]; const float* ca_bv=(const float*)d_in[17];
  const float* caWo =(const float*)d_in[18]; const float* ca_bo=(const float*)d_in[19];
  const float* g1=(const float*)d_in[20]; const float* be1=(const float*)d_in[21];
  const float* g2=(const float*)d_in[22]; const float* be2=(const float*)d_in[23];
  const float* g3=(const float*)d_in[24]; const float* be3=(const float*)d_in[25];
  const float* Wff1=(const float*)d_in[26]; const float* b_ff1=(const float*)d_in[27];
  const float* Wff2=(const float*)d_in[28]; const float* b_ff2=(const float*)d_in[29];
  const float* Wvm=(const float*)d_in[30];  const float* b_vm=(const float*)d_in[31];
  const float* Wvr=(const float*)d_in[32];  const float* b_vr=(const float*)d_in[33];

  k_init<<<1,256,0,stream>>>(b_vm, (float*)(ws+OFF_PE), (u16*)(ws+OFF_EMB), (float*)(ws+OFF_LOSS), (unsigned*)(ws+OFF_BAR));

  k_f2bf<<<512,256,0,stream>>>(saWq,(u16*)(ws+OFF_WQ),1048576);
  k_f2bf<<<512,256,0,stream>>>(saWk,(u16*)(ws+OFF_WK),1048576);
  k_f2bf<<<512,256,0,stream>>>(saWv,(u16*)(ws+OFF_WV),1048576);
  k_f2bf<<<512,256,0,stream>>>(saWo,(u16*)(ws+OFF_WO),1048576);
  k_f2bf<<<512,256,0,stream>>>(caWq,(u16*)(ws+OFF_CAWQ),1048576);
  k_f2bf<<<512,256,0,stream>>>(caWo,(u16*)(ws+OFF_CAWO),1048576);
  k_f2bf<<<1024,256,0,stream>>>(Wff1,(u16*)(ws+OFF_FF1),2097152);
  k_f2bf<<<1024,256,0,stream>>>(Wff2,(u16*)(ws+OFF_FF2),2097152);
  k_f2bf<<<702,256,0,stream>>>(Wvr,(u16*)(ws+OFF_WVR),1437696);

  k_tr<<<24*32,256,0,stream>>>(W_af, 1024, 768, (u16*)(ws+OFF_WAFT), 1024);
  k_tr<<<32*44,256,0,stream>>>(Wvr, 1404, 1024, (u16*)(ws+OFF_WVRT), 1408);

  k_gemm_pre<<<64*48,256,0,stream>>>(caWk, 1024, 1024, 1024, (const u16*)(ws+OFF_WAFT), (u16*)(ws+OFF_WKP), 768, 48);
  k_gemm_pre<<<64*48,256,0,stream>>>(caWv, 1024, 1024, 1024, (const u16*)(ws+OFF_WAFT), (u16*)(ws+OFF_WVP), 768, 48);
  k_gemm_pre<<<64*64,256,0,stream>>>(Wvm, 1404, 1404, 1408, (const u16*)(ws+OFF_WVRT), (u16*)(ws+OFF_MB), 1024, 64);

  k_bvec<<<12,256,0,stream>>>(caWk, ca_bk, b_af, caWv, ca_bv, Wvm, b_vr, b_vm,
                              (float*)(ws+OFF_BKP),(float*)(ws+OFF_BVP),(float*)(ws+OFF_BCOMB));

  k_mem<<<9600,256,0,stream>>>(audio, (const u16*)(ws+OFF_WKP),(const u16*)(ws+OFF_WVP),
                               (const float*)(ws+OFF_BKP),(const float*)(ws+OFF_BVP),
                               (u16*)(ws+OFF_MEMK),(u16*)(ws+OFF_MEMV));

  LoopArgs la{ sa_bq, sa_bk, sa_bv, sa_bo, ca_bq, ca_bo, b_ff1, b_ff2,
               g1, be1, g2, be2, g3, be3, ws };
  k_loop<<<256,256,0,stream>>>(la);

  k_loss<<<825,256,0,stream>>>((const u16*)(ws+OFF_U3S),(const float*)(ws+OFF_ST3),
                               (const u16*)(ws+OFF_WVR), b_vr, g3, be3, vert, (float*)(ws+OFF_LOSS));
  k_fin<<<1,64,0,stream>>>((const float*)(ws+OFF_LOSS), (float*)d_out);
}

// Round 7
// 36207.520 us; speedup vs baseline: 5.5935x; 1.2652x over previous
//
#include <hip/hip_runtime.h>

typedef unsigned short u16;
typedef short s16x8 __attribute__((ext_vector_type(8)));
typedef float f32x4 __attribute__((ext_vector_type(4)));
typedef float f32x2 __attribute__((ext_vector_type(2)));

#define DEV static __device__ __forceinline__

DEV float bf2f(u16 h){ union{unsigned u;float f;} v; v.u=((unsigned)h)<<16; return v.f; }
DEV u16 f2bf(float f){ union{float f;unsigned u;} v; v.f=f; unsigned u=v.u; return (u16)((u + 0x7fffu + ((u>>16)&1u))>>16); }

// ---------------- device-coherent IO (sc0 sc1 -> coherence point; no fences anywhere) ----------------
DEV void st2_dc(u16* p, u16 v){
  unsigned vv = v;
  asm volatile("global_store_short %0, %1, off sc0 sc1" :: "v"(p), "v"(vv) : "memory");
}
DEV void st16_dc(void* p, s16x8 v){
  asm volatile("global_store_dwordx4 %0, %1, off sc0 sc1" :: "v"(p), "v"(v) : "memory");
}
DEV void stf_dc(float* p, float v){
  asm volatile("global_store_dword %0, %1, off sc0 sc1" :: "v"(p), "v"(v) : "memory");
}
DEV u16 ld2_dc(const u16* p){
  unsigned r;
  asm volatile("global_load_ushort %0, %1, off sc0 sc1\n\ts_waitcnt vmcnt(0)" : "=&v"(r) : "v"(p) : "memory");
  return (u16)r;
}
DEV void vmwait0(){ asm volatile("s_waitcnt vmcnt(0)" ::: "memory"); }

// MFMA A-fragment loads: 8 x 16B at 64B stride + single waitcnt, all inside ONE asm block
// (outputs unusable until block completes -> no hoisting hazard).
DEV void ldf8_dc(const u16* p, s16x8* o){
  asm volatile(
    "global_load_dwordx4 %0, %8, off sc0 sc1\n\t"
    "global_load_dwordx4 %1, %8, off offset:64 sc0 sc1\n\t"
    "global_load_dwordx4 %2, %8, off offset:128 sc0 sc1\n\t"
    "global_load_dwordx4 %3, %8, off offset:192 sc0 sc1\n\t"
    "global_load_dwordx4 %4, %8, off offset:256 sc0 sc1\n\t"
    "global_load_dwordx4 %5, %8, off offset:320 sc0 sc1\n\t"
    "global_load_dwordx4 %6, %8, off offset:384 sc0 sc1\n\t"
    "global_load_dwordx4 %7, %8, off offset:448 sc0 sc1\n\t"
    "s_waitcnt vmcnt(0)"
    : "=&v"(o[0]),"=&v"(o[1]),"=&v"(o[2]),"=&v"(o[3]),
      "=&v"(o[4]),"=&v"(o[5]),"=&v"(o[6]),"=&v"(o[7])
    : "v"(p) : "memory");
}
// + residual ushort
DEV void ldf8r_dc(const u16* p, s16x8* o, const u16* pr, unsigned* rr){
  asm volatile(
    "global_load_dwordx4 %0, %9, off sc0 sc1\n\t"
    "global_load_dwordx4 %1, %9, off offset:64 sc0 sc1\n\t"
    "global_load_dwordx4 %2, %9, off offset:128 sc0 sc1\n\t"
    "global_load_dwordx4 %3, %9, off offset:192 sc0 sc1\n\t"
    "global_load_dwordx4 %4, %9, off offset:256 sc0 sc1\n\t"
    "global_load_dwordx4 %5, %9, off offset:320 sc0 sc1\n\t"
    "global_load_dwordx4 %6, %9, off offset:384 sc0 sc1\n\t"
    "global_load_dwordx4 %7, %9, off offset:448 sc0 sc1\n\t"
    "global_load_ushort %8, %10, off sc0 sc1\n\t"
    "s_waitcnt vmcnt(0)"
    : "=&v"(o[0]),"=&v"(o[1]),"=&v"(o[2]),"=&v"(o[3]),
      "=&v"(o[4]),"=&v"(o[5]),"=&v"(o[6]),"=&v"(o[7]),"=&v"(*rr)
    : "v"(p), "v"(pr) : "memory");
}
// + residual ushort + f32x2 stats
DEV void ldf8rs_dc(const u16* p, s16x8* o, const u16* pr, unsigned* rr, const float* ps, f32x2* ss){
  asm volatile(
    "global_load_dwordx4 %0, %10, off sc0 sc1\n\t"
    "global_load_dwordx4 %1, %10, off offset:64 sc0 sc1\n\t"
    "global_load_dwordx4 %2, %10, off offset:128 sc0 sc1\n\t"
    "global_load_dwordx4 %3, %10, off offset:192 sc0 sc1\n\t"
    "global_load_dwordx4 %4, %10, off offset:256 sc0 sc1\n\t"
    "global_load_dwordx4 %5, %10, off offset:320 sc0 sc1\n\t"
    "global_load_dwordx4 %6, %10, off offset:384 sc0 sc1\n\t"
    "global_load_dwordx4 %7, %10, off offset:448 sc0 sc1\n\t"
    "global_load_ushort %8, %11, off sc0 sc1\n\t"
    "global_load_dwordx2 %9, %12, off sc0 sc1\n\t"
    "s_waitcnt vmcnt(0)"
    : "=&v"(o[0]),"=&v"(o[1]),"=&v"(o[2]),"=&v"(o[3]),
      "=&v"(o[4]),"=&v"(o[5]),"=&v"(o[6]),"=&v"(o[7]),"=&v"(*rr),"=&v"(*ss)
    : "v"(p), "v"(pr), "v"(ps) : "memory");
}
// 16 frags (K=2048 row: half0 at +0.., half1 at +2048B..) + ushort + f32x2
DEV void ldf16rs_dc(const u16* p, s16x8* o, const u16* pr, unsigned* rr, const float* ps, f32x2* ss){
  asm volatile(
    "global_load_dwordx4 %0, %18, off sc0 sc1\n\t"
    "global_load_dwordx4 %1, %18, off offset:64 sc0 sc1\n\t"
    "global_load_dwordx4 %2, %18, off offset:128 sc0 sc1\n\t"
    "global_load_dwordx4 %3, %18, off offset:192 sc0 sc1\n\t"
    "global_load_dwordx4 %4, %18, off offset:256 sc0 sc1\n\t"
    "global_load_dwordx4 %5, %18, off offset:320 sc0 sc1\n\t"
    "global_load_dwordx4 %6, %18, off offset:384 sc0 sc1\n\t"
    "global_load_dwordx4 %7, %18, off offset:448 sc0 sc1\n\t"
    "global_load_dwordx4 %8, %18, off offset:2048 sc0 sc1\n\t"
    "global_load_dwordx4 %9, %18, off offset:2112 sc0 sc1\n\t"
    "global_load_dwordx4 %10, %18, off offset:2176 sc0 sc1\n\t"
    "global_load_dwordx4 %11, %18, off offset:2240 sc0 sc1\n\t"
    "global_load_dwordx4 %12, %18, off offset:2304 sc0 sc1\n\t"
    "global_load_dwordx4 %13, %18, off offset:2368 sc0 sc1\n\t"
    "global_load_dwordx4 %14, %18, off offset:2432 sc0 sc1\n\t"
    "global_load_dwordx4 %15, %18, off offset:2496 sc0 sc1\n\t"
    "global_load_ushort %16, %19, off sc0 sc1\n\t"
    "global_load_dwordx2 %17, %20, off sc0 sc1\n\t"
    "s_waitcnt vmcnt(0)"
    : "=&v"(o[0]),"=&v"(o[1]),"=&v"(o[2]),"=&v"(o[3]),
      "=&v"(o[4]),"=&v"(o[5]),"=&v"(o[6]),"=&v"(o[7]),
      "=&v"(o[8]),"=&v"(o[9]),"=&v"(o[10]),"=&v"(o[11]),
      "=&v"(o[12]),"=&v"(o[13]),"=&v"(o[14]),"=&v"(o[15]),
      "=&v"(*rr),"=&v"(*ss)
    : "v"(p), "v"(pr), "v"(ps) : "memory");
}

// ---------------- workspace layout (bytes) ----------------
constexpr size_t SZ_DD = (size_t)1024*1024*2;
constexpr size_t OFF_WQ=0;
constexpr size_t OFF_WK=OFF_WQ+SZ_DD;
constexpr size_t OFF_WV=OFF_WK+SZ_DD;
constexpr size_t OFF_WO=OFF_WV+SZ_DD;
constexpr size_t OFF_CAWQ=OFF_WO+SZ_DD;
constexpr size_t OFF_CAWO=OFF_CAWQ+SZ_DD;
constexpr size_t OFF_FF1=OFF_CAWO+SZ_DD;                    // 2048x1024 bf16
constexpr size_t OFF_FF2=OFF_FF1+(size_t)2048*1024*2;       // 1024 rows x 2048 K bf16
constexpr size_t OFF_MB =OFF_FF2+(size_t)2048*1024*2;       // 1024x1024 bf16 (Wvm@Wvr)
constexpr size_t OFF_WVR=OFF_MB+SZ_DD;                      // 1404x1024 bf16
constexpr size_t OFF_WKP=OFF_WVR+(size_t)1404*1024*2;       // 1024x768 bf16
constexpr size_t OFF_WVP=OFF_WKP+(size_t)1024*768*2;
constexpr size_t OFF_WAFT=OFF_WVP+(size_t)1024*768*2;       // 768x1024 bf16 (W_af^T)
constexpr size_t OFF_WVRT=OFF_WAFT+(size_t)768*1024*2;      // 1024x1408 bf16 (Wvr^T padded)
constexpr size_t OFF_PE  =OFF_WVRT+(size_t)1024*1408*2;     // 25x1024 f32
constexpr size_t OFF_BKP =OFF_PE+25*1024*4;                 // 1024 f32
constexpr size_t OFF_BVP =OFF_BKP+4096;
constexpr size_t OFF_BCOMB=OFF_BVP+4096;
constexpr size_t OFF_MEMK=OFF_BCOMB+4096;                   // oct layout [16][4][32][1200][8] bf16
constexpr size_t OFF_MEMV=OFF_MEMK+(size_t)16*1200*1024*2;  // [b*1200+s][1024]
constexpr size_t OFF_KC  =OFF_MEMV+(size_t)16*1200*1024*2;  // [(t*16+b)][1024] bf16 (write-once slots)
constexpr size_t OFF_VC  =OFF_KC+(size_t)600*16*1024*2;
constexpr size_t OFF_U3S =OFF_VC+(size_t)600*16*1024*2;     // 600x16x1024 bf16
constexpr size_t OFF_ST3 =OFF_U3S+(size_t)600*16*1024*2;    // 600x16x2 f32
constexpr size_t OFF_EMB =OFF_ST3+600*32*4;                 // 16x1024 bf16
constexpr size_t OFF_QB  =OFF_EMB+32768;
constexpr size_t OFF_SC  =OFF_QB+32768;                     // (reserved)
constexpr size_t OFF_SA  =OFF_SC+(size_t)16*4*608*4;
constexpr size_t OFF_U1  =OFF_SA+32768;
constexpr size_t OFF_ST1 =OFF_U1+32768;                     // 32 f32
constexpr size_t OFF_Q2  =OFF_ST1+256;
constexpr size_t OFF_CA  =OFF_Q2+32768;
constexpr size_t OFF_U2  =OFF_CA+32768;
constexpr size_t OFF_ST2 =OFF_U2+32768;
constexpr size_t OFF_HH  =OFF_ST2+256;                      // 16x2048 bf16
constexpr size_t OFF_LOSS=OFF_HH+65536;
constexpr size_t OFF_BAR =OFF_LOSS+256;                     // 256 x 128B all-to-all slots
constexpr size_t WS_NEED =OFF_BAR+32768;

// GEMM 16x16 tile with A-fragments in registers, B from swizzled LDS weight slot.
// a[j] covers k = k0 + 32*j + [0..8). 4-wave K-split, partials reduced via FB.
DEV float gemm_frag(const s16x8* a, const u16* slot, float* FB){
  int tid=threadIdx.x, wv=tid>>6, ln=tid&63;
  int r=ln&15, kq=ln>>4;
  int k0=wv*256 + kq*8;
  int sw=(r&7)<<3;
  const u16* bp = slot + r*1024;
  f32x4 acc={0.f,0.f,0.f,0.f};
  #pragma unroll
  for(int j=0;j<8;j++)
    acc = __builtin_amdgcn_mfma_f32_16x16x32_bf16(a[j], *(const s16x8*)(bp + ((k0+32*j)^sw)), acc, 0,0,0);
  #pragma unroll
  for(int j=0;j<4;j++) FB[wv*256 + (kq*4+j)*16 + r] = acc[j];
  __syncthreads();
  int row=tid>>4, col=tid&15;
  float s=(FB[row*16+col]+FB[256+row*16+col])+(FB[512+row*16+col]+FB[768+row*16+col]);
  __syncthreads();
  return s;
}

// in-register LayerNorm over fragment set; stats via RB reduction into STm/STr.
DEV void ln_frags(s16x8* a, const float* g, const float* be, int k0, int r, float* RB, float* STm, float* STr){
  int tid=threadIdx.x;
  float sum=0.f, sq=0.f;
  #pragma unroll
  for(int j=0;j<8;j++){
    #pragma unroll
    for(int e=0;e<8;e++){ float f=bf2f((u16)a[j][e]); sum+=f; sq+=f*f; }
  }
  RB[tid]=sum; RB[256+tid]=sq;
  __syncthreads();
  if (tid<16){
    float S=0.f,Q=0.f;
    #pragma unroll
    for(int q=0;q<16;q++){ S+=RB[tid+16*q]; Q+=RB[256+tid+16*q]; }
    float m=S*(1.f/1024.f); float var=Q*(1.f/1024.f)-m*m;
    STm[tid]=m; STr[tid]=rsqrtf(var+1e-5f);
  }
  __syncthreads();
  float m=STm[r], rs=STr[r];
  const float* gg=g+k0; const float* bb=be+k0;
  #pragma unroll
  for(int j=0;j<8;j++){
    s16x8 o;
    #pragma unroll
    for(int e=0;e<8;e++){ int k=32*j+e; float f=(bf2f((u16)a[j][e])-m)*rs*gg[k]+bb[k]; o[e]=(short)f2bf(f); }
    a[j]=o;
  }
}

// copy one 16x1024 bf16 weight tile into swizzled LDS slot (cached reads: prep-written, immutable)
DEV void copy_slot(const u16* src, int rstride, u16* dst){
  int row=threadIdx.x>>4, k0=(threadIdx.x&15)<<6;
  int sw=(row&7)<<3;
  const u16* s = src + (size_t)row*rstride + k0;
  u16* d = dst + row*1024;
  #pragma unroll
  for(int c=0;c<64;c+=8)
    *(s16x8*)(d + (((k0+c))^sw)) = *(const s16x8*)(s+c);
}

// grid barrier: all-to-all. vmcnt drains sc0sc1 stores; each block posts epoch to own slot;
// 256 threads poll 256 slots concurrently. No fences, no RMW.
DEV void gbar(char* barb, unsigned& epoch, int wg){
  vmwait0();
  __syncthreads();
  unsigned target = epoch + 1u;
  if (threadIdx.x == 0)
    __hip_atomic_store((unsigned*)(barb + (wg<<7)), target, __ATOMIC_RELAXED, __HIP_MEMORY_SCOPE_AGENT);
  {
    unsigned* s = (unsigned*)(barb + (threadIdx.x<<7));
    while (__hip_atomic_load(s, __ATOMIC_RELAXED, __HIP_MEMORY_SCOPE_AGENT) < target)
      __builtin_amdgcn_s_sleep(1);
  }
  __syncthreads();
  epoch++;
}

// ---------------- prep kernels ----------------
__global__ void __launch_bounds__(256) k_init(const float* b_vm, float* pe, u16* emb, float* loss, unsigned* bar){
  int tid=threadIdx.x;
  if (tid==0) loss[0]=0.f;
  for(int idx=tid; idx<8192; idx+=256) bar[idx]=0u;
  for(int idx=tid; idx<16384; idx+=256) emb[idx] = f2bf(b_vm[idx&1023]);
  for(int idx=tid; idx<25600; idx+=256){
    int p_=idx>>10, d_=idx&1023; int m=d_>>1;
    float div = expf(-(float)(2*m) * (9.210340372f/1024.f));
    float a = (float)p_ * div;
    pe[idx] = (d_&1)? cosf(a) : sinf(a);
  }
}

__global__ void __launch_bounds__(256) k_f2bf(const float* s, u16* d, int n){
  int idx=(blockIdx.x*256+threadIdx.x)*8;
  if (idx < n){
    #pragma unroll
    for(int j=0;j<8;j++) d[idx+j]=f2bf(s[idx+j]);
  }
}

__global__ void __launch_bounds__(256) k_tr(const float* src, int R, int C, u16* dst, int ldd){
  __shared__ float TL[32][33];
  int cb=(C+31)/32;
  int bj=blockIdx.x%cb, br=blockIdx.x/cb;
  int j0=bj*32, r0=br*32;
  int lj=threadIdx.x&31, lr=threadIdx.x>>5;
  #pragma unroll
  for(int p=0;p<4;p++){ int rr=r0+lr+p*8, jj=j0+lj;
    TL[lr+p*8][lj] = (rr<R && jj<C)? src[(size_t)rr*C+jj] : 0.f; }
  __syncthreads();
  #pragma unroll
  for(int p=0;p<4;p++){ int jj=j0+lr+p*8, rr=r0+lj;
    if (jj<C && rr<ldd) dst[(size_t)jj*ldd+rr] = f2bf(TL[lj][lr+p*8]); }
}

DEV float gemm_tile16g(const u16* SLu, int lds_stride, const u16* W, int Kext, int wstride, int colbase, float* FB){
  int tid=threadIdx.x, wv=tid>>6, ln=tid&63;
  int r=ln&15, kq=ln>>4;
  int kpw=Kext>>2, k0=wv*kpw;
  const u16* ap = SLu + r*lds_stride + k0 + kq*8;
  const u16* bp = W + (size_t)(colbase+r)*wstride + k0 + kq*8;
  f32x4 acc={0.f,0.f,0.f,0.f};
  for(int k=0;k<kpw;k+=32)
    acc = __builtin_amdgcn_mfma_f32_16x16x32_bf16(*(const s16x8*)(ap+k), *(const s16x8*)(bp+k), acc, 0,0,0);
  #pragma unroll
  for(int j=0;j<4;j++) FB[wv*256 + (kq*4+j)*16 + r] = acc[j];
  __syncthreads();
  int row=tid>>4, col=tid&15;
  float s=(FB[row*16+col]+FB[256+row*16+col])+(FB[512+row*16+col]+FB[768+row*16+col]);
  __syncthreads();
  return s;
}

__global__ void __launch_bounds__(256) k_gemm_pre(const float* A, int lda, int Kreal, int Kpad,
                                                  const u16* Bw, u16* out, int ldo, int Ntiles){
  __shared__ u16 SL[16*1416];
  __shared__ float FB[1024];
  int bx=blockIdx.x; int mt=bx/Ntiles, nt=bx%Ntiles;
  int tid=threadIdx.x;
  int cpt = Kpad>>4;
  { int row=tid>>4, c0=(tid&15)*cpt;
    const float* s=A + (size_t)(mt*16+row)*lda;
    u16* d=SL + row*(Kpad+8);
    for(int c=0;c<cpt;c++){ int k=c0+c; d[k] = (k<Kreal)? f2bf(s[k]) : (u16)0; }
    __syncthreads();
  }
  float v = gemm_tile16g(SL, Kpad+8, Bw, Kpad, Kpad, nt*16, FB);
  int row=tid>>4, col=tid&15;
  out[(size_t)(mt*16+row)*ldo + nt*16+col] = f2bf(v);
}

__global__ void __launch_bounds__(256) k_bvec(const float* caWk, const float* ca_bk, const float* b_af,
                                              const float* caWv, const float* ca_bv,
                                              const float* Wvm, const float* b_vr, const float* b_vm,
                                              float* bkp, float* bvp, float* bcomb){
  __shared__ float VB[1408];
  int seg=blockIdx.x>>2, ch=blockIdx.x&3; int o=ch*256+threadIdx.x;
  const float* vec = (seg==2)? b_vr : b_af; int K = (seg==2)?1404:1024;
  for(int k=threadIdx.x;k<K;k+=256) VB[k]=vec[k];
  __syncthreads();
  const float* Arow = (seg==0)? caWk+(size_t)o*1024 : (seg==1)? caWv+(size_t)o*1024 : Wvm+(size_t)o*1404;
  float s=0.f;
  for(int k=0;k<K;k++) s += Arow[k]*VB[k];
  if(seg==0) bkp[o]=s+ca_bk[o]; else if(seg==1) bvp[o]=s+ca_bv[o]; else bcomb[o]=s+b_vm[o];
}

__global__ void __launch_bounds__(256) k_mem(const float* audio, const u16* wkp, const u16* wvp,
                                             const float* bkp, const float* bvp, u16* mt8, u16* memv){
  __shared__ u16 SL[16*776];
  int bx=blockIdx.x; int mt=bx>>3, cbk=bx&7;
  int tid=threadIdx.x, wv=tid>>6, ln=tid&63;
  { int row=tid>>4, c0=(tid&15)*48;
    const float* s = audio + (size_t)(mt*16+row)*768 + c0;
    u16* d = SL + row*776 + c0;
    #pragma unroll
    for(int c=0;c<48;c+=8){ s16x8 o;
      #pragma unroll
      for(int j=0;j<8;j++) o[j]=(short)f2bf(s[c+j]);
      *(s16x8*)(d+c)=o; }
    __syncthreads();
  }
  int r=ln&15, kq=ln>>4;
  const u16* ap = SL + r*776 + kq*8;
  for(int rep=0;rep<2;rep++){
    int colb = cbk*128 + wv*32 + rep*16;
    for(int mat=0;mat<2;mat++){
      const u16* W = mat? wvp : wkp;
      const u16* bp = W + (size_t)(colb+r)*768 + kq*8;
      f32x4 acc={0.f,0.f,0.f,0.f};
      for(int k=0;k<768;k+=32)
        acc = __builtin_amdgcn_mfma_f32_16x16x32_bf16(*(const s16x8*)(ap+k), *(const s16x8*)(bp+k), acc, 0,0,0);
      const float* bias = mat? bvp:bkp;
      int o = colb + r;
      float bo = bias[o];
      #pragma unroll
      for(int j=0;j<4;j++){ int row_=kq*4+j;
        int g = mt*16+row_;
        float val = acc[j] + bo;
        if (mat){
          memv[(size_t)g*1024 + o] = f2bf(val);
        } else {
          int bb=g/1200, ss=g-bb*1200;
          mt8[(((size_t)(bb*4 + (o>>8))*32 + ((o&255)>>3))*1200 + ss)*8 + (o&7)] = f2bf(val);
        }
      }
    }
  }
}

// ---------------- main sequential loop (plain launch, 256 co-resident blocks) ----------------
struct LoopArgs {
  const float *sa_bq,*sa_bk,*sa_bv,*sa_bo,*ca_bq,*ca_bo,*b_ff1,*b_ff2;
  const float *g1,*be1,*g2,*be2,*g3,*be3;
  char* ws;
};

__global__ void __launch_bounds__(256,1) k_loop(LoopArgs A){
  __shared__ u16 WL[3*16*1024];      // 96 KB swizzled resident weight slots
  __shared__ float FB[1024];         // 4 KB
  __shared__ float PL[608];
  __shared__ float RB[640];
  __shared__ float STm[16], STr[16]; // ~106 KB LDS -> 1 wg/CU, 256 co-resident

  char* ws = A.ws;
  const u16* wq   =(const u16*)(ws+OFF_WQ);
  const u16* wk   =(const u16*)(ws+OFF_WK);
  const u16* wv_  =(const u16*)(ws+OFF_WV);
  const u16* wo   =(const u16*)(ws+OFF_WO);
  const u16* cawq =(const u16*)(ws+OFF_CAWQ);
  const u16* cawo =(const u16*)(ws+OFF_CAWO);
  const u16* ff1  =(const u16*)(ws+OFF_FF1);
  const u16* ff2  =(const u16*)(ws+OFF_FF2);
  const u16* mb   =(const u16*)(ws+OFF_MB);
  const float* pe =(const float*)(ws+OFF_PE);
  const float* bcomb=(const float*)(ws+OFF_BCOMB);
  const u16* mt8  =(const u16*)(ws+OFF_MEMK);
  const u16* memv =(const u16*)(ws+OFF_MEMV);
  u16* kc =(u16*)(ws+OFF_KC);
  u16* vc =(u16*)(ws+OFF_VC);
  u16* u3s=(u16*)(ws+OFF_U3S);
  float* st3=(float*)(ws+OFF_ST3);
  u16* emb=(u16*)(ws+OFF_EMB);
  u16* qb =(u16*)(ws+OFF_QB);
  u16* sab=(u16*)(ws+OFF_SA);
  u16* u1 =(u16*)(ws+OFF_U1);
  float* st1=(float*)(ws+OFF_ST1);
  u16* q2b=(u16*)(ws+OFF_Q2);
  u16* cab=(u16*)(ws+OFF_CA);
  u16* u2 =(u16*)(ws+OFF_U2);
  float* st2=(float*)(ws+OFF_ST2);
  u16* hh =(u16*)(ws+OFF_HH);
  char* barb=(char*)(ws+OFF_BAR);

  unsigned epoch = 0;
  int wg = blockIdx.x, tid = threadIdx.x;
  int row = tid>>4, lo = tid&15;
  int wv = tid>>6, ln = tid&63;
  int fr = ln&15, kq = ln>>4;
  int k0 = wv*256 + kq*8;           // fragment k-base (u16 elems)
  int grp = wg>>6, ct = (wg&63)<<4;

  // ---- one-time: preload weight tiles into LDS (swizzled) ----
  {
    u16* s0d = WL;          u16* s1d = WL+16384;  u16* s2d = WL+32768;
    if (grp==0){
      copy_slot(wq  +(size_t)ct*1024,1024,s0d);
      copy_slot(cawq+(size_t)ct*1024,1024,s1d);
      copy_slot(ff1 +(size_t)ct*1024,1024,s2d);
    } else if (grp==1){
      copy_slot(wk  +(size_t)ct*1024,1024,s0d);
      copy_slot(cawo+(size_t)ct*1024,1024,s1d);
      copy_slot(ff1 +((size_t)(1024+ct))*1024,1024,s2d);
    } else if (grp==2){
      copy_slot(wv_ +(size_t)ct*1024,1024,s0d);
      copy_slot(ff2 +(size_t)ct*2048,2048,s1d);
      copy_slot(ff2 +(size_t)ct*2048+1024,2048,s2d);
    } else {
      copy_slot(wo  +(size_t)ct*1024,1024,s0d);
      copy_slot(mb  +(size_t)ct*1024,1024,s1d);
    }
    __syncthreads();
  }
  const u16* SLOT0 = WL;
  const u16* SLOT1 = WL+16384;
  const u16* SLOT2 = WL+32768;

  #pragma unroll 1
  for (int i=0;i<600;i++){
    int ip = i%25;

    // ---- phase A: x = emb + pe ; q/k/v projections (192 wgs) ----
    if (wg < 192){
      s16x8 f[8];
      ldf8_dc(emb + fr*1024 + k0, f);
      const float* pp = pe + ip*1024 + k0;
      #pragma unroll
      for(int j=0;j<8;j++){ s16x8 o;
        #pragma unroll
        for(int e=0;e<8;e++) o[e]=(short)f2bf(bf2f((u16)f[j][e]) + pp[32*j+e]);
        f[j]=o; }
      const float* bias = (grp==0)? A.sa_bq : (grp==1)? A.sa_bk : A.sa_bv;
      float v = gemm_frag(f,SLOT0,FB);
      int o = ct + lo;
      u16 bv = f2bf(v + bias[o]);
      if (grp==0)      st2_dc(qb + row*1024 + o, bv);
      else if (grp==1) st2_dc(kc + ((size_t)i*16+row)*1024 + o, bv);
      else             st2_dc(vc + ((size_t)i*16+row)*1024 + o, bv);
    }
    gbar(barb, epoch, wg);

    // ---- phase B: self-attn (b,h) (64 wgs); K/V cached (write-once slots); online softmax ----
    if (wg < 64){
      int b=wg>>2, h=wg&3, cnt=i+1;
      RB[tid] = bf2f(ld2_dc(qb + b*1024 + h*256 + tid));
      __syncthreads();
      float sl = 1.0f/(float)(4<<(2*h));
      float mloc=-1e30f, lloc=0.f;
      for(int t=tid; t<cnt; t+=256){
        const u16* kr = kc + ((size_t)t*16 + b)*1024 + h*256;
        float s=0.f;
        #pragma unroll
        for(int c=0;c<256;c+=8){
          s16x8 k8 = *(const s16x8*)(kr+c);
          #pragma unroll
          for(int j=0;j<8;j++) s += RB[c+j]*bf2f((u16)k8[j]);
        }
        s = s*0.0625f - sl*(float)((i-t)/25);
        PL[t]=s;
        float M = fmaxf(mloc, s);
        lloc = lloc*__expf(mloc-M) + __expf(s-M);
        mloc = M;
      }
      #pragma unroll
      for(int off=32; off>0; off>>=1){
        float m2=__shfl_xor(mloc,off), l2=__shfl_xor(lloc,off);
        float M=fmaxf(mloc,m2);
        lloc = lloc*__expf(mloc-M) + l2*__expf(m2-M);
        mloc = M;
      }
      if (ln==0){ RB[576+2*wv]=mloc; RB[577+2*wv]=lloc; }
      __syncthreads();
      float M=-1e30f, L=0.f;
      #pragma unroll
      for(int w=0;w<4;w++){
        float m2=RB[576+2*w], l2=RB[577+2*w];
        float Mn=fmaxf(M,m2);
        L = L*__expf(M-Mn) + l2*__expf(m2-Mn);
        M = Mn;
      }
      float rl = 1.0f/L;
      int d_oct = tid>>3, t_ln = tid&7;
      const u16* vcb = vc + (size_t)b*1024 + h*256 + d_oct*8;
      float acc[8]={0.f,0.f,0.f,0.f,0.f,0.f,0.f,0.f};
      for(int t=t_ln; t<cnt; t+=8){
        s16x8 v8 = *(const s16x8*)(vcb + (size_t)t*16384);
        float p = __expf(PL[t]-M);
        #pragma unroll
        for(int jj=0;jj<8;jj++) acc[jj] += p*bf2f((u16)v8[jj]);
      }
      #pragma unroll
      for(int j=0;j<8;j++){
        acc[j] += __shfl_xor(acc[j],1);
        acc[j] += __shfl_xor(acc[j],2);
        acc[j] += __shfl_xor(acc[j],4);
      }
      if (t_ln==0){
        s16x8 o8;
        #pragma unroll
        for(int j=0;j<8;j++) o8[j]=(short)f2bf(acc[j]*rl);
        st16_dc(sab + b*1024 + h*256 + d_oct*8, o8);
      }
    }
    gbar(barb, epoch, wg);

    // ---- phase C: u1 = x + sa@Wo^T + bo (wgs 192..255) ----
    if (wg>=192){
      s16x8 f[8]; unsigned er;
      ldf8r_dc(sab + fr*1024 + k0, f, emb + row*1024 + ct + lo, &er);
      float v = gemm_frag(f,SLOT0,FB);
      int o = ct+lo;
      float x = bf2f((u16)er) + pe[ip*1024+o];
      st2_dc(u1 + row*1024 + o, f2bf(x + v + A.sa_bo[o]));
    }
    gbar(barb, epoch, wg);

    // ---- phase D: q2 = LN1(u1)@caWq^T + bq (wgs 0..63) ----
    if (wg<64){
      s16x8 f[8];
      ldf8_dc(u1 + fr*1024 + k0, f);
      ln_frags(f, A.g1, A.be1, k0, fr, RB, STm, STr);
      float v = gemm_frag(f,SLOT1,FB);
      int o=ct+lo;
      st2_dc(q2b + row*1024+o, f2bf(v + A.ca_bq[o]));
      if (wg==0 && tid<16){ stf_dc(st1+tid*2, STm[tid]); stf_dc(st1+tid*2+1, STr[tid]); }
    }
    gbar(barb, epoch, wg);

    // ---- phase E: windowed cross-attn -> ca (wgs 0..63); memk/memv cached (prep-written) ----
    if (wg<64){
      int b=wg>>2, h=wg&3;
      RB[tid] = bf2f(ld2_dc(q2b + b*1024 + h*256 + tid));
      __syncthreads();
      int s0 = 2*i-6; if(s0<0)s0=0;
      int s1 = 2*i+2; if(s1>1200)s1=1200;
      int ns = s1-s0;
      int si=tid>>5, dl=tid&31;
      float p=0.f;
      if (si<ns){
        const u16* MT = mt8 + (((size_t)(b*4+h)*32 + dl)*1200 + (s0+si))*8;
        s16x8 m8 = *(const s16x8*)MT;
        #pragma unroll
        for(int j=0;j<8;j++) p += RB[dl*8+j]*bf2f((u16)m8[j]);
      }
      #pragma unroll
      for(int o2=16;o2>0;o2>>=1) p += __shfl_xor(p,o2);
      if (dl==0 && si<ns) RB[512+si] = p*0.0625f;
      __syncthreads();
      float mx=-1e30f;
      for(int q=0;q<ns;q++) mx=fmaxf(mx,RB[512+q]);
      float l=0.f, acc=0.f;
      for(int q=0;q<ns;q++){
        float e=__expf(RB[512+q]-mx); l+=e;
        acc += e*bf2f(memv[(size_t)(b*1200+s0+q)*1024 + h*256 + tid]);
      }
      st2_dc(cab + b*1024+h*256+tid, f2bf(acc/l));
    }
    gbar(barb, epoch, wg);

    // ---- phase F: u2 = x1 + ca@caWo^T + bo2 (wgs 64..127) ----
    if (wg>=64 && wg<128){
      s16x8 f[8]; unsigned ur; f32x2 sv;
      ldf8rs_dc(cab + fr*1024 + k0, f, u1 + row*1024 + ct + lo, &ur, st1 + row*2, &sv);
      float v = gemm_frag(f,SLOT1,FB);
      int o=ct+lo;
      float x1 = (bf2f((u16)ur)-sv[0])*sv[1]*A.g1[o] + A.be1[o];
      st2_dc(u2+row*1024+o, f2bf(x1 + v + A.ca_bo[o]));
    }
    gbar(barb, epoch, wg);

    // ---- phase G: hh = relu(LN2(u2)@FF1^T + b1) (wgs 0..127) ----
    if (wg<128){
      s16x8 f[8];
      ldf8_dc(u2 + fr*1024 + k0, f);
      ln_frags(f, A.g2, A.be2, k0, fr, RB, STm, STr);
      float v = gemm_frag(f,SLOT2,FB);
      int o=(wg<<4)+lo;
      st2_dc(hh+row*2048+o, f2bf(fmaxf(v + A.b_ff1[o], 0.f)));
      if (wg==0 && tid<16){ stf_dc(st2+tid*2,STm[tid]); stf_dc(st2+tid*2+1,STr[tid]); }
    }
    gbar(barb, epoch, wg);

    // ---- phase H: u3 = x2 + hh@FF2^T + b2 (wgs 128..191; K=2048, both halves one load round) ----
    if (wg>=128 && wg<192){
      s16x8 f[16]; unsigned ur; f32x2 sv;
      ldf16rs_dc(hh + fr*2048 + k0, f, u2 + row*1024 + ct + lo, &ur, st2 + row*2, &sv);
      float v = gemm_frag(f,SLOT1,FB);
      v += gemm_frag(f+8,SLOT2,FB);
      int o=ct+lo;
      float x2 = (bf2f((u16)ur)-sv[0])*sv[1]*A.g2[o] + A.be2[o];
      st2_dc(u3s + ((size_t)i*16+row)*1024+o, f2bf(x2 + v + A.b_ff2[o]));
    }
    gbar(barb, epoch, wg);

    // ---- phase I: emb = LN3(u3)@M^T + bcomb (wgs 192..255) ----
    if (wg>=192){
      s16x8 f[8];
      ldf8_dc(u3s + (size_t)i*16384 + fr*1024 + k0, f);
      ln_frags(f, A.g3, A.be3, k0, fr, RB, STm, STr);
      float v = gemm_frag(f,SLOT1,FB);
      int o=ct+lo;
      st2_dc(emb+row*1024+o, f2bf(v + bcomb[o]));
      if (wg==192 && tid<16){ st3[i*32+tid*2]=STm[tid]; st3[i*32+tid*2+1]=STr[tid]; }  // read post-kernel
    }
    gbar(barb, epoch, wg);
  }
}

// ---------------- deferred loss ----------------
__global__ void __launch_bounds__(256) k_loss(const u16* u3s, const float* st3, const u16* wvr,
                                              const float* bvr, const float* g3, const float* be3,
                                              const float* vert, float* loss){
  __shared__ u16 SL[16*1032];
  __shared__ float R[64];
  int bx=blockIdx.x; int ib=bx/11, cb=bx%11;
  int tid=threadIdx.x, wvv=tid>>6, ln=tid&63;
  int r=ln&15, kq=ln>>4;
  float lsum=0.f;
  for(int ii=0;ii<8;ii++){
    int i=ib*8+ii;
    { int row=tid>>4, c0=(tid&15)<<6;
      float m=st3[i*32+row*2], rs=st3[i*32+row*2+1];
      const u16* s=u3s + (size_t)(i*16+row)*1024 + c0;
      u16* d=SL + row*1032 + c0;
      #pragma unroll
      for(int c=0;c<64;c+=8){ s16x8 v=*(const s16x8*)(s+c); s16x8 o;
        #pragma unroll
        for(int j=0;j<8;j++){ int cc=c0+c+j; o[j]=(short)f2bf((bf2f((u16)v[j])-m)*rs*g3[cc]+be3[cc]); }
        *(s16x8*)(d+c)=o; }
      __syncthreads();
    }
    const u16* ap = SL + r*1032 + kq*8;
    for(int rep=0;rep<2;rep++){
      int colb = cb*128 + wvv*32 + rep*16;
      int o_r = colb + r; bool ok = o_r < 1404;
      const u16* bp = wvr + (size_t)(ok? o_r:0)*1024 + kq*8;
      f32x4 acc={0.f,0.f,0.f,0.f};
      for(int k=0;k<1024;k+=32)
        acc = __builtin_amdgcn_mfma_f32_16x16x32_bf16(*(const s16x8*)(ap+k), *(const s16x8*)(bp+k), acc, 0,0,0);
      if (ok){
        float bo = bvr[o_r];
        #pragma unroll
        for(int j=0;j<4;j++){
          int b_=kq*4+j;
          float ov = acc[j] + bo;
          float vt = vert[(size_t)(b_*600 + i)*1404 + o_r];
          float dd = ov - vt; lsum += dd*dd;
        }
      }
    }
    __syncthreads();
  }
  #pragma unroll
  for(int o=32;o>0;o>>=1) lsum += __shfl_down(lsum,o);
  if (ln==0) R[wvv]=lsum;
  __syncthreads();
  if (tid==0) atomicAdd(loss, (R[0]+R[1])+(R[2]+R[3]));
}

__global__ void k_fin(const float* loss, float* dout){
  if (threadIdx.x==0) dout[0] = loss[0] * (1.f/13478400.f);   // / (16*600*1404)
}

// ---------------- host ----------------
extern "C" void kernel_launch(void* const* d_in, const int* in_sizes, int n_in,
                              void* d_out, int out_size, void* d_ws, size_t ws_size,
                              hipStream_t stream){
  char* ws = (char*)d_ws;
  if (ws_size < WS_NEED){ hipMemsetAsync(d_out, 0, 4, stream); return; }

  const float* audio=(const float*)d_in[0];
  const float* vert =(const float*)d_in[1];
  const float* W_af =(const float*)d_in[2];
  const float* b_af =(const float*)d_in[3];
  const float* saWq =(const float*)d_in[4];  const float* sa_bq=(const float*)d_in[5];
  const float* saWk =(const float*)d_in[6];  const float* sa_bk=(const float*)d_in[7];
  const float* saWv =(const float*)d_in[8];  const float* sa_bv=(const float*)d_in[9];
  const float* saWo =(const float*)d_in[10]; const float* sa_bo=(const float*)d_in[11];
  const float* caWq =(const float*)d_in[12]; const float* ca_bq=(const float*)d_in[13];
  const float* caWk =(const float*)d_in[14]; const float* ca_bk=(const float*)d_in[15];
  const float* caWv =(const float*)d_in[16]; const float* ca_bv=(const float*)d_in[17];
  const float* caWo =(const float*)d_in[18]; const float* ca_bo=(const float*)d_in[19];
  const float* g1=(const float*)d_in[20]; const float* be1=(const float*)d_in[21];
  const float* g2=(const float*)d_in[22]; const float* be2=(const float*)d_in[23];
  const float* g3=(const float*)d_in[24]; const float* be3=(const float*)d_in[25];
  const float* Wff1=(const float*)d_in[26]; const float* b_ff1=(const float*)d_in[27];
  const float* Wff2=(const float*)d_in[28]; const float* b_ff2=(const float*)d_in[29];
  const float* Wvm=(const float*)d_in[30];  const float* b_vm=(const float*)d_in[31];
  const float* Wvr=(const float*)d_in[32];  const float* b_vr=(const float*)d_in[33];

  k_init<<<1,256,0,stream>>>(b_vm, (float*)(ws+OFF_PE), (u16*)(ws+OFF_EMB), (float*)(ws+OFF_LOSS), (unsigned*)(ws+OFF_BAR));

  k_f2bf<<<512,256,0,stream>>>(saWq,(u16*)(ws+OFF_WQ),1048576);
  k_f2bf<<<512,256,0,stream>>>(saWk,(u16*)(ws+OFF_WK),1048576);
  k_f2bf<<<512,256,0,stream>>>(saWv,(u16*)(ws+OFF_WV),1048576);
  k_f2bf<<<512,256,0,stream>>>(saWo,(u16*)(ws+OFF_WO),1048576);
  k_f2bf<<<512,256,0,stream>>>(caWq,(u16*)(ws+OFF_CAWQ),1048576);
  k_f2bf<<<512,256,0,stream>>>(caWo,(u16*)(ws+OFF_CAWO),1048576);
  k_f2bf<<<1024,256,0,stream>>>(Wff1,(u16*)(ws+OFF_FF1),2097152);
  k_f2bf<<<1024,256,0,stream>>>(Wff2,(u16*)(ws+OFF_FF2),2097152);
  k_f2bf<<<702,256,0,stream>>>(Wvr,(u16*)(ws+OFF_WVR),1437696);

  k_tr<<<24*32,256,0,stream>>>(W_af, 1024, 768, (u16*)(ws+OFF_WAFT), 1024);
  k_tr<<<32*44,256,0,stream>>>(Wvr, 1404, 1024, (u16*)(ws+OFF_WVRT), 1408);

  k_gemm_pre<<<64*48,256,0,stream>>>(caWk, 1024, 1024, 1024, (const u16*)(ws+OFF_WAFT), (u16*)(ws+OFF_WKP), 768, 48);
  k_gemm_pre<<<64*48,256,0,stream>>>(caWv, 1024, 1024, 1024, (const u16*)(ws+OFF_WAFT), (u16*)(ws+OFF_WVP), 768, 48);
  k_gemm_pre<<<64*64,256,0,stream>>>(Wvm, 1404, 1404, 1408, (const u16*)(ws+OFF_WVRT), (u16*)(ws+OFF_MB), 1024, 64);

  k_bvec<<<12,256,0,stream>>>(caWk, ca_bk, b_af, caWv, ca_bv, Wvm, b_vr, b_vm,
                              (float*)(ws+OFF_BKP),(float*)(ws+OFF_BVP),(float*)(ws+OFF_BCOMB));

  k_mem<<<9600,256,0,stream>>>(audio, (const u16*)(ws+OFF_WKP),(const u16*)(ws+OFF_WVP),
                               (const float*)(ws+OFF_BKP),(const float*)(ws+OFF_BVP),
                               (u16*)(ws+OFF_MEMK),(u16*)(ws+OFF_MEMV));

  LoopArgs la{ sa_bq, sa_bk, sa_bv, sa_bo, ca_bq, ca_bo, b_ff1, b_ff2,
               g1, be1, g2, be2, g3, be3, ws };
  k_loop<<<256,256,0,stream>>>(la);

  k_loss<<<825,256,0,stream>>>((const u16*)(ws+OFF_U3S),(const float*)(ws+OFF_ST3),
                               (const u16*)(ws+OFF_WVR), b_vr, g3, be3, vert, (float*)(ws+OFF_LOSS));
  k_fin<<<1,64,0,stream>>>((const float*)(ws+OFF_LOSS), (float*)d_out);
}